// Round 10
// baseline (400.108 us; speedup 1.0000x reference)
//
#include <hip/hip_runtime.h>

typedef unsigned short u16;
typedef unsigned int   u32;
typedef short  bfrag   __attribute__((ext_vector_type(8)));   // 8 bf16 = 4 VGPR
typedef float  accfrag __attribute__((ext_vector_type(16)));  // 32x32 C/D
typedef unsigned int   u32x4 __attribute__((ext_vector_type(4)));
typedef unsigned short u16x4 __attribute__((ext_vector_type(4)));
typedef float          f32x4 __attribute__((ext_vector_type(4)));

#define B_SZ 8
#define C_SZ 512
#define T_SZ 1024
#define NH   8
#define DK   64

// 1/sqrt(d_k) * 1/ln(2): folded into Q projection; softmax runs in exp2 domain
#define QSCL 0.18033688f

__device__ __forceinline__ u16 f2bf(float f) {
  u32 u = __float_as_uint(f);
  u = u + 0x7fffu + ((u >> 16) & 1u);   // RNE
  return (u16)(u >> 16);
}

// single v_exp_f32 (exp2f libm path is ~10 instrs — measured VALU regression r4)
__device__ __forceinline__ float fexp2(float x) {
  return __builtin_amdgcn_exp2f(x);
}

__device__ __forceinline__ u32 cvtpk(float lo, float hi) {
  u32 r;
  asm("v_cvt_pk_bf16_f32 %0, %1, %2" : "=v"(r) : "v"(lo), "v"(hi));
  return r;
}

__device__ __forceinline__ void permswap(u32 &a, u32 &b) {
  asm volatile("v_permlane32_swap_b32 %0, %1" : "+v"(a), "+v"(b));
}

// async global->LDS, 16B per lane; LDS dest is wave-uniform base + lane*16
__device__ __forceinline__ void gload16(const u16* g, u16* l) {
  __builtin_amdgcn_global_load_lds(
      (const __attribute__((address_space(1))) void*)g,
      (__attribute__((address_space(3))) void*)l, 16, 0, 0);
}

// ---- merged: W' = W * inv (bf16); b' = b*inv + beta - mean*inv -----------
__global__ void prep_wb(const float* __restrict__ Ws, const float* __restrict__ bs,
                        const float* __restrict__ gam, const float* __restrict__ beta,
                        const float* __restrict__ mean, const float* __restrict__ var,
                        u16* __restrict__ Wp, float* __restrict__ bp) {
  int bx = blockIdx.x;
  if (bx < 4096) {
    int idx = bx * 256 + threadIdx.x;            // 4*512*512
    int io = idx >> 9;                           // i*512 + o
    float inv = gam[io] * rsqrtf(var[io] + 1e-5f);
    Wp[idx] = f2bf(Ws[idx] * inv);
  } else {
    int idx = (bx - 4096) * 256 + threadIdx.x;   // 2048
    float inv = gam[idx] * rsqrtf(var[idx] + 1e-5f);
    bp[idx] = bs[idx] * inv + beta[idx] - mean[idx] * inv;
  }
}

// ---- in[b][c][t] f32 -> Xt[src][b][t][c] bf16; k,v also copied to cache --
__global__ void transpose_cvt(const float* __restrict__ q, const float* __restrict__ k,
                              const float* __restrict__ v, u16* __restrict__ Xt,
                              float* __restrict__ cache) {
  __shared__ float tile[32][33];
  int z = blockIdx.z;
  int src = z >> 3, b = z & 7;
  const float* in = (src == 0) ? q : ((src == 1) ? k : v);
  u16* out = Xt + (size_t)src * ((size_t)B_SZ * T_SZ * C_SZ);
  int t0 = blockIdx.x * 32, c0 = blockIdx.y * 32;
  int tx = threadIdx.x & 31, ty = threadIdx.x >> 5;
#pragma unroll
  for (int rr = 0; rr < 4; ++rr) {
    int c = c0 + ty + rr * 8;
    float val = in[(((size_t)b * C_SZ + c) << 10) + t0 + tx];
    tile[ty + rr * 8][tx] = val;
    if (src >= 1) {   // cache = concat(key, value) along channel dim
      int cc = c + (src == 2 ? 512 : 0);
      cache[((size_t)b << 20) + ((size_t)cc << 10) + t0 + tx] = val;
    }
  }
  __syncthreads();
#pragma unroll
  for (int rr = 0; rr < 4; ++rr) {
    int t = t0 + ty + rr * 8;
    out[(((size_t)b << 10) + t) * C_SZ + c0 + tx] = f2bf(tile[tx][ty + rr * 8]);
  }
}

// ---- mask (B,1,T,T) int32 -> bit-plane mbT[b][s/32][t] -------------------
__global__ void mask_bits(const int* __restrict__ mask, u32* __restrict__ mbT) {
  int w = blockIdx.x * 256 + threadIdx.x;        // 262144
  int bt = w >> 5;                               // b*1024 + t
  int st = w & 31;
  const int* mrow = mask + ((size_t)bt << 10) + (st << 5);
  u32 word = 0;
#pragma unroll
  for (int j = 0; j < 32; j += 4) {
    int4 m4 = *(const int4*)(mrow + j);
    word |= (m4.x != 0 ? 1u : 0u) << j;
    word |= (m4.y != 0 ? 1u : 0u) << (j + 1);
    word |= (m4.z != 0 ? 1u : 0u) << (j + 2);
    word |= (m4.w != 0 ? 1u : 0u) << (j + 3);
  }
  int b = bt >> 10, t = bt & 1023;
  mbT[(((size_t)b * 32 + st) << 10) + t] = word;
}

// ---- fused QKV projection GEMM (one dispatch, 768 blocks = 3/CU) ---------
// src = blockIdx.z>>3: 0->Qf (scaled by QSCL), 1->Kf, 2->Vf fragment layouts
// K-loop: reg-prefetch pipeline (load kt+1 under compute kt) + XOR-swizzled LDS
__launch_bounds__(256, 4)
__global__ void gemm_qkv(const u16* __restrict__ Wp, const float* __restrict__ bpA,
                         const u16* __restrict__ Xt,
                         u16* __restrict__ Qf, u16* __restrict__ Kf, u16* __restrict__ Vf) {
  __shared__ __align__(16) u16 lds[2 * 128 * 64];
  int tid = threadIdx.x;
  int src = blockIdx.z >> 3;
  int b   = blockIdx.z & 7;
  int t0 = blockIdx.x * 128;
  int o0 = blockIdx.y * 128;
  int wid = tid >> 6, lane = tid & 63;
  int ln = lane & 31, hi = lane >> 5;
  int wr = wid >> 1, wc = wid & 1;

  const u16* Wsrc = Wp + (size_t)src * 262144;
  const float* bp = bpA + src * 512;
  const u16* Xin  = Xt + (size_t)src * ((size_t)B_SZ * T_SZ * C_SZ);
  u16* Yout = (src == 0) ? Qf : (src == 1 ? Kf : Vf);

  const char* Ag = (const char*)Wsrc;                                    // rows: o (1024 B stride)
  const char* Bg = (const char*)(Xin + (((size_t)b << 10) + t0) * C_SZ); // rows: t-local
  char* ldsA = (char*)lds;
  char* ldsB = (char*)lds + 16384;

  accfrag acc[2][2];
#pragma unroll
  for (int m2 = 0; m2 < 2; ++m2)
#pragma unroll
    for (int n2 = 0; n2 < 2; ++n2)
#pragma unroll
      for (int e = 0; e < 16; ++e) acc[m2][n2][e] = 0.f;

  int lin = tid * 16;
  u32x4 ra[4], rb[4];
#pragma unroll
  for (int it = 0; it < 4; ++it) {   // prologue: load kt=0
    int off = lin + it * 4096;
    int r = off >> 7, cb = off & 127;
    ra[it] = *(const u32x4*)(Ag + (size_t)(o0 + r) * 1024 + cb);
    rb[it] = *(const u32x4*)(Bg + (size_t)r * 1024 + cb);
  }

  for (int kt = 0; kt < 8; ++kt) {
    __syncthreads();   // LDS free (previous compute done by all waves)
#pragma unroll
    for (int it = 0; it < 4; ++it) {
      int off = lin + it * 4096;
      int swz = off ^ (((off >> 7) & 7) << 4);   // bank swizzle (G4)
      *(u32x4*)(ldsA + swz) = ra[it];
      *(u32x4*)(ldsB + swz) = rb[it];
    }
    __syncthreads();   // LDS ready
    if (kt < 7) {      // prefetch kt+1; latency hides under the MFMA cluster
#pragma unroll
      for (int it = 0; it < 4; ++it) {
        int off = lin + it * 4096;
        int r = off >> 7, cb = off & 127;
        ra[it] = *(const u32x4*)(Ag + (size_t)(o0 + r) * 1024 + (kt + 1) * 128 + cb);
        rb[it] = *(const u32x4*)(Bg + (size_t)r * 1024 + (kt + 1) * 128 + cb);
      }
    }
#pragma unroll
    for (int kk = 0; kk < 4; ++kk) {
      int csw = (kk * 32 + hi * 16) ^ ((ln & 7) << 4);   // swizzled col
      bfrag a[2], bb[2];
#pragma unroll
      for (int m2 = 0; m2 < 2; ++m2)
        a[m2] = *(const bfrag*)(ldsA + (wr * 64 + m2 * 32 + ln) * 128 + csw);
#pragma unroll
      for (int n2 = 0; n2 < 2; ++n2)
        bb[n2] = *(const bfrag*)(ldsB + (wc * 64 + n2 * 32 + ln) * 128 + csw);
#pragma unroll
      for (int m2 = 0; m2 < 2; ++m2)
#pragma unroll
        for (int n2 = 0; n2 < 2; ++n2)
          acc[m2][n2] = __builtin_amdgcn_mfma_f32_32x32x16_bf16(a[m2], bb[n2], acc[m2][n2], 0, 0, 0);
    }
  }

  float oscl = (src == 0) ? QSCL : 1.0f;
#pragma unroll
  for (int m2 = 0; m2 < 2; ++m2) {
    int obase = o0 + wr * 64 + m2 * 32;
#pragma unroll
    for (int n2 = 0; n2 < 2; ++n2) {
      int t = t0 + wc * 64 + n2 * 32 + ln;
      if (src < 2) {
        // Q/K fragment layout: [(b*8+h)*32 + t/32][dd>>4][(t&31)+32*((dd>>3)&1)][dd&7]
        int tt5 = t & 31, st = t >> 5;
#pragma unroll
        for (int g = 0; g < 4; ++g) {
          int d0 = obase + 8 * g + 4 * hi;
          int hh = d0 >> 6, dd = d0 & 63;
          u16x4 pk4;
#pragma unroll
          for (int qq = 0; qq < 4; ++qq)
            pk4[qq] = f2bf((acc[m2][n2][4 * g + qq] + bp[d0 + qq]) * oscl);
          size_t a = ((((size_t)b * 8 + hh) * 32 + st) << 11)
                   + (size_t)((dd >> 4) * 512 + (tt5 + 32 * ((dd >> 3) & 1)) * 8 + (dd & 7));
          *(u16x4*)(Yout + a) = pk4;
        }
      } else {
        // V-fragment layout: fi=((s>>4)&1)*2+((dd>>5)&1), l=(dd&31)+((s>>3)&1)*32
        int s = t, st = s >> 5;
#pragma unroll
        for (int r = 0; r < 16; ++r) {
          int d = obase + (r & 3) + 8 * (r >> 2) + 4 * hi;
          int hh = d >> 6, dd = d & 63;
          int fi = ((s >> 4) & 1) * 2 + ((dd >> 5) & 1);
          int l  = (dd & 31) + ((s >> 3) & 1) * 32;
          Yout[((((size_t)b * 8 + hh) * 32 + st) << 11)
               + (size_t)(fi * 512 + l * 8 + (s & 7))] = f2bf(acc[m2][n2][r] + bp[d]);
        }
      }
    }
  }
}

// ---- out projection GEMM: f32 natural [b][c][t] --------------------------
// 128(o) x 64(t) tiles -> 512 blocks = 2/CU. Reg-prefetch + swizzle; LDS 24KB.
__launch_bounds__(256, 4)
__global__ void gemm_out(const u16* __restrict__ Wp, const float* __restrict__ bp,
                         const u16* __restrict__ Xin, float* __restrict__ Yout) {
  __shared__ __align__(16) char ldsc[24576];   // A 16KB | B 8KB
  int tid = threadIdx.x;
  int b  = blockIdx.z;
  int t0 = blockIdx.x * 64;
  int o0 = blockIdx.y * 128;
  int wid = tid >> 6, lane = tid & 63;
  int ln = lane & 31, hi = lane >> 5;
  int wr = wid >> 1, wc = wid & 1;

  const char* Ag = (const char*)Wp;                                      // rows: o
  const char* Bg = (const char*)(Xin + (((size_t)b << 10) + t0) * C_SZ); // rows: t-local
  char* ldsA = ldsc;
  char* ldsB = ldsc + 16384;

  accfrag acc[2];
#pragma unroll
  for (int m2 = 0; m2 < 2; ++m2)
#pragma unroll
    for (int e = 0; e < 16; ++e) acc[m2][e] = 0.f;

  int lin = tid * 16;
  u32x4 ra[4], rb[2];
#pragma unroll
  for (int it = 0; it < 4; ++it) {
    int off = lin + it * 4096;
    int r = off >> 7, cb = off & 127;
    ra[it] = *(const u32x4*)(Ag + (size_t)(o0 + r) * 1024 + cb);
  }
#pragma unroll
  for (int it = 0; it < 2; ++it) {
    int off = lin + it * 4096;
    int r = off >> 7, cb = off & 127;
    rb[it] = *(const u32x4*)(Bg + (size_t)r * 1024 + cb);
  }

  for (int kt = 0; kt < 8; ++kt) {
    __syncthreads();
#pragma unroll
    for (int it = 0; it < 4; ++it) {
      int off = lin + it * 4096;
      int swz = off ^ (((off >> 7) & 7) << 4);
      *(u32x4*)(ldsA + swz) = ra[it];
    }
#pragma unroll
    for (int it = 0; it < 2; ++it) {
      int off = lin + it * 4096;
      int swz = off ^ (((off >> 7) & 7) << 4);
      *(u32x4*)(ldsB + swz) = rb[it];
    }
    __syncthreads();
    if (kt < 7) {
#pragma unroll
      for (int it = 0; it < 4; ++it) {
        int off = lin + it * 4096;
        int r = off >> 7, cb = off & 127;
        ra[it] = *(const u32x4*)(Ag + (size_t)(o0 + r) * 1024 + (kt + 1) * 128 + cb);
      }
#pragma unroll
      for (int it = 0; it < 2; ++it) {
        int off = lin + it * 4096;
        int r = off >> 7, cb = off & 127;
        rb[it] = *(const u32x4*)(Bg + (size_t)r * 1024 + (kt + 1) * 128 + cb);
      }
    }
#pragma unroll
    for (int kk = 0; kk < 4; ++kk) {
      int csw = (kk * 32 + hi * 16) ^ ((ln & 7) << 4);
      bfrag a[2], bb;
#pragma unroll
      for (int m2 = 0; m2 < 2; ++m2)
        a[m2] = *(const bfrag*)(ldsA + (wr * 64 + m2 * 32 + ln) * 128 + csw);
      bb = *(const bfrag*)(ldsB + (wc * 32 + ln) * 128 + csw);
#pragma unroll
      for (int m2 = 0; m2 < 2; ++m2)
        acc[m2] = __builtin_amdgcn_mfma_f32_32x32x16_bf16(a[m2], bb, acc[m2], 0, 0, 0);
    }
  }

#pragma unroll
  for (int m2 = 0; m2 < 2; ++m2) {
    int obase = o0 + wr * 64 + m2 * 32;
    int t = t0 + wc * 32 + ln;
#pragma unroll
    for (int r = 0; r < 16; ++r) {
      int o = obase + (r & 3) + 8 * (r >> 2) + 4 * hi;
      Yout[(((size_t)b * C_SZ + o) << 10) + t] = acc[m2][r] + bp[o];
    }
  }
}

// ---- fused flash attention, 4-way s-split, single-buffer read-early ------
// 1024 blocks x 512 thr: 4 s-groups x 2 q-tiles. Per iter: read LDS frags to
// regs -> barrier -> DMA next tile into SAME buffer -> compute from regs ->
// barrier(drain). DMA hides under compute; LDS only 34KB -> 4 blocks/CU =
// 32 waves/CU (r7's failure was stage->immediate-drain, not the 4-way split).
__launch_bounds__(512, 8)
__global__ void attn_fused(const u16* __restrict__ Qf, const u16* __restrict__ Kf,
                           const u16* __restrict__ Vf, const u32* __restrict__ mbT,
                           u16* __restrict__ X2) {
  __shared__ __align__(16) char smem[34816];  // 32KB stage/merge + 2KB m/l
  float* mlb = (float*)(smem + 32768);        // [slot:8][ln:32][2] f32

  int n = blockIdx.x;
  int bh = n & 63, tb = n >> 6;               // tb 0..15
  int b = bh >> 3, h = bh & 7;
  int tid = threadIdx.x;
  int wid = tid >> 6, lane = tid & 63;
  int grp = wid >> 1, wl = wid & 1;           // grp 0..3 (s-quarter), wl 0..1 (q-tile)
  int ln = lane & 31, hi = lane >> 5;
  int tt = tb * 2 + wl;                       // q-tile 0..31
  int t  = tt * 32 + ln;

  // Q fragments: one coalesced 1KB load per j
  const u16* QfT = Qf + (((size_t)bh * 32 + tt) << 11);
  bfrag qf[4];
#pragma unroll
  for (int j = 0; j < 4; ++j)
    qf[j] = *(const bfrag*)(QfT + j * 512 + lane * 8);

  const u16* KfB = Kf + ((size_t)bh << 16);
  const u16* VfB = Vf + ((size_t)bh << 16);
  const u32* mcol = mbT + ((size_t)b << 15) + t;

  // m_run floor -1e4: masked scores stay -1e30 -> exp2(-1e30-m) == +0 in HW.
  float m_run = -1.0e4f, l_run = 0.f;
  accfrag accd[2];
#pragma unroll
  for (int m2 = 0; m2 < 2; ++m2)
#pragma unroll
    for (int e = 0; e < 16; ++e) accd[m2][e] = 0.f;

  int gid = tid & 127;                        // thread id within group (2 waves)
  u16* sK = (u16*)smem + grp * 4096;          // 4KB K + 4KB V per group
  u16* sV = sK + 2048;
  int st0 = grp * 8;

  // prologue: stage tile st0, load mask word
  {
    size_t tn = (size_t)st0 << 11;
    gload16(KfB + tn + gid * 8,        sK + gid * 8);
    gload16(KfB + tn + 1024 + gid * 8, sK + 1024 + gid * 8);
    gload16(VfB + tn + gid * 8,        sV + gid * 8);
    gload16(VfB + tn + 1024 + gid * 8, sV + 1024 + gid * 8);
  }
  u32 mw = mcol[st0 << 10];
  __syncthreads();                            // tile 0 DMA drained

  for (int it = 0; it < 8; ++it) {
    int st = st0 + it;

    // 1) LDS -> regs (lane-linear, conflict-free b128)
    bfrag kf[4], vf[4];
#pragma unroll
    for (int j = 0; j < 4; ++j) {
      kf[j] = *(const bfrag*)(sK + j * 512 + lane * 8);
      vf[j] = *(const bfrag*)(sV + j * 512 + lane * 8);
    }
    __syncthreads();                          // all reads done; buffer free

    // 2) DMA next tile into the same buffer; hides under compute below
    u32 mn = 0;
    if (it < 7) {
      size_t tn = (size_t)(st + 1) << 11;
      gload16(KfB + tn + gid * 8,        sK + gid * 8);
      gload16(KfB + tn + 1024 + gid * 8, sK + 1024 + gid * 8);
      gload16(VfB + tn + gid * 8,        sV + gid * 8);
      gload16(VfB + tn + 1024 + gid * 8, sV + 1024 + gid * 8);
      mn = mcol[(st + 1) << 10];
    }

    // 3) QK^T (S already in log2 units: Q pre-scaled)
    accfrag S;
#pragma unroll
    for (int e = 0; e < 16; ++e) S[e] = 0.f;
    __builtin_amdgcn_s_setprio(1);
#pragma unroll
    for (int j = 0; j < 4; ++j)
      S = __builtin_amdgcn_mfma_f32_32x32x16_bf16(kf[j], qf[j], S, 0, 0, 0);
    __builtin_amdgcn_s_setprio(0);

    // ---- softmax over key rows (per-lane: 16 of 32 rows; partner lane^32)
    u32 mbits = mw >> (4 * hi);
    float p[16];
#pragma unroll
    for (int r = 0; r < 16; ++r) {
      int pos = (r & 3) + 8 * (r >> 2);
      p[r] = ((mbits >> pos) & 1u) ? S[r] : -1e30f;
    }
    float q8[8], q4[4];
#pragma unroll
    for (int r = 0; r < 8; ++r) q8[r] = fmaxf(p[r], p[r + 8]);
#pragma unroll
    for (int r = 0; r < 4; ++r) q4[r] = fmaxf(q8[r], q8[r + 4]);
    float pmax = fmaxf(fmaxf(q4[0], q4[1]), fmaxf(q4[2], q4[3]));
    pmax = fmaxf(pmax, __shfl_xor(pmax, 32));

    // deferred rescale (T13): 8 nats = 11.54 bits
    if (__any(pmax > m_run + 11.5f)) {
      float m_new = fmaxf(m_run, pmax);
      float alpha = fexp2(m_run - m_new);
      l_run *= alpha;
#pragma unroll
      for (int m2 = 0; m2 < 2; ++m2)
#pragma unroll
        for (int e = 0; e < 16; ++e) accd[m2][e] *= alpha;
      m_run = m_new;
    }

#pragma unroll
    for (int r = 0; r < 16; ++r)
      p[r] = fexp2(p[r] - m_run);             // masked: exp2(-1e30) == +0
    float s8[8], s4[4];
#pragma unroll
    for (int r = 0; r < 8; ++r) s8[r] = p[r] + p[r + 8];
#pragma unroll
    for (int r = 0; r < 4; ++r) s4[r] = s8[r] + s8[r + 4];
    float psum = (s4[0] + s4[1]) + (s4[2] + s4[3]);
    psum += __shfl_xor(psum, 32);
    l_run += psum;

    // P (D-layout) -> B-operand bf16 frags: 8 cvt_pk + 4 permlane32_swap
    bfrag pf[2];
#pragma unroll
    for (int j2 = 0; j2 < 2; ++j2) {
      u32 A0 = cvtpk(p[8 * j2 + 0], p[8 * j2 + 1]);
      u32 A1 = cvtpk(p[8 * j2 + 2], p[8 * j2 + 3]);
      u32 B0 = cvtpk(p[8 * j2 + 4], p[8 * j2 + 5]);
      u32 B1 = cvtpk(p[8 * j2 + 6], p[8 * j2 + 7]);
      permswap(A0, B0);
      permswap(A1, B1);
      union { u32 u[4]; bfrag f; } pu;
      pu.u[0] = A0; pu.u[1] = A1; pu.u[2] = B0; pu.u[3] = B1;
      pf[j2] = pu.f;
    }
    __builtin_amdgcn_s_setprio(1);
#pragma unroll
    for (int j2 = 0; j2 < 2; ++j2)
#pragma unroll
      for (int m2 = 0; m2 < 2; ++m2)
        accd[m2] = __builtin_amdgcn_mfma_f32_32x32x16_bf16(vf[j2 * 2 + m2], pf[j2], accd[m2], 0, 0, 0);
    __builtin_amdgcn_s_setprio(0);

    __syncthreads();                          // drains next-tile DMA
    mw = mn;
  }

  // ---- 4-way merge through LDS (reusing the 32KB stage region) ----------
  float* comb = (float*)smem;
  // (last loop barrier already passed; stage region free)
  // Round 1: grps 1,3 publish; grps 0,2 absorb
  if (grp & 1) {
    float* dst = comb + ((grp >> 1) * 4096 + wl * 2048);
#pragma unroll
    for (int m2 = 0; m2 < 2; ++m2)
#pragma unroll
      for (int e = 0; e < 16; ++e)
        dst[(m2 * 16 + e) * 64 + lane] = accd[m2][e];
    if (hi == 0) {
      mlb[((grp * 2 + wl) * 32 + ln) * 2]     = m_run;
      mlb[((grp * 2 + wl) * 32 + ln) * 2 + 1] = l_run;
    }
  }
  __syncthreads();
  if (!(grp & 1)) {
    int pg = grp + 1;
    const float* srcp = comb + ((pg >> 1) * 4096 + wl * 2048);
    float m1 = mlb[((pg * 2 + wl) * 32 + ln) * 2];
    float l1 = mlb[((pg * 2 + wl) * 32 + ln) * 2 + 1];
    float M  = fmaxf(m_run, m1);
    float w0 = fexp2(m_run - M), w1 = fexp2(m1 - M);
    l_run = l_run * w0 + l1 * w1;
    m_run = M;
#pragma unroll
    for (int m2 = 0; m2 < 2; ++m2)
#pragma unroll
      for (int e = 0; e < 16; ++e)
        accd[m2][e] = accd[m2][e] * w0 + srcp[(m2 * 16 + e) * 64 + lane] * w1;
  }
  __syncthreads();
  // Round 2: grp 2 publishes; grp 0 absorbs + writes out
  if (grp == 2) {
    float* dst = comb + wl * 2048;
#pragma unroll
    for (int m2 = 0; m2 < 2; ++m2)
#pragma unroll
      for (int e = 0; e < 16; ++e)
        dst[(m2 * 16 + e) * 64 + lane] = accd[m2][e];
    if (hi == 0) {
      mlb[((4 + wl) * 32 + ln) * 2]     = m_run;
      mlb[((4 + wl) * 32 + ln) * 2 + 1] = l_run;
    }
  }
  __syncthreads();
  if (grp == 0) {
    const float* srcp = comb + wl * 2048;
    float m1 = mlb[((4 + wl) * 32 + ln) * 2];
    float l1 = mlb[((4 + wl) * 32 + ln) * 2 + 1];
    float M  = fmaxf(m_run, m1);
    float w0 = fexp2(m_run - M), w1 = fexp2(m1 - M);
    float l  = l_run * w0 + l1 * w1;
    float invl = (l > 0.f) ? 1.f / l : 0.f;
    u16* Orow = X2 + (((size_t)b << 10) + t) * C_SZ + h * DK;
#pragma unroll
    for (int m2 = 0; m2 < 2; ++m2)
#pragma unroll
      for (int g = 0; g < 4; ++g) {
        u16x4 pk4;
#pragma unroll
        for (int qq = 0; qq < 4; ++qq) {
          int e = 4 * g + qq;
          float v2 = srcp[(m2 * 16 + e) * 64 + lane];
          pk4[qq] = f2bf((accd[m2][e] * w0 + v2 * w1) * invl);
        }
        *(u16x4*)(Orow + m2 * 32 + 8 * g + 4 * hi) = pk4;
      }
  }
}

extern "C" void kernel_launch(void* const* d_in, const int* in_sizes, int n_in,
                              void* d_out, int out_size, void* d_ws, size_t ws_size,
                              hipStream_t stream) {
  (void)in_sizes; (void)n_in; (void)out_size; (void)ws_size;
  const float* q    = (const float*)d_in[0];
  const float* k    = (const float*)d_in[1];
  const float* v    = (const float*)d_in[2];
  const int*   mask = (const int*)d_in[3];
  const float* Ws   = (const float*)d_in[4];
  const float* bs   = (const float*)d_in[5];
  const float* gam  = (const float*)d_in[6];
  const float* beta = (const float*)d_in[7];
  const float* mean = (const float*)d_in[8];
  const float* var  = (const float*)d_in[9];

  float* out   = (float*)d_out;
  float* cache = out + (size_t)B_SZ * C_SZ * T_SZ;     // 4,194,304 floats

  const size_t ARR = (size_t)B_SZ * T_SZ * C_SZ;       // 4,194,304 elems
  char* ws = (char*)d_ws;
  u16*   Wp = (u16*)(ws);                              // 4*512*512 bf16 = 2 MB
  float* bp = (float*)(ws + 2097152);                  // 2048 f32
  u16*   Xt = (u16*)(ws + 2162688);                    // 3 * ARR bf16
  u16*   Qt = Xt + 3 * ARR;                            // Qf fragment layout
  u16*   Kt = Qt + ARR;                                // Kf fragment layout
  u16*   Vb = Kt + ARR;                                // Vf fragment layout
  u16*   X2 = Vb + ARR;
  u32*   mb = (u32*)((char*)(X2 + ARR));               // 262144 words = 1 MB

  prep_wb<<<4104, 256, 0, stream>>>(Ws, bs, gam, beta, mean, var, Wp, bp);
  transpose_cvt<<<dim3(32, 16, 24), 256, 0, stream>>>(q, k, v, Xt, cache);
  mask_bits<<<1024, 256, 0, stream>>>(mask, mb);

  gemm_qkv<<<dim3(8, 4, 24), 256, 0, stream>>>(Wp, bp, Xt, Qt, Kt, Vb);
  attn_fused<<<1024, 512, 0, stream>>>(Qt, Kt, Vb, mb, X2);
  gemm_out<<<dim3(16, 4, 8), 256, 0, stream>>>(Wp + 786432, bp + 1536, X2, out);
}

// Round 11
// 99.989 us; speedup vs baseline: 4.0015x; 4.0015x over previous
//
#include <hip/hip_runtime.h>

typedef unsigned short u16;
typedef unsigned int   u32;
typedef short  bfrag   __attribute__((ext_vector_type(8)));   // 8 bf16 = 4 VGPR
typedef float  accfrag __attribute__((ext_vector_type(16)));  // 32x32 C/D
typedef unsigned int   u32x4 __attribute__((ext_vector_type(4)));
typedef unsigned short u16x4 __attribute__((ext_vector_type(4)));
typedef float          f32x4 __attribute__((ext_vector_type(4)));

#define B_SZ 8
#define C_SZ 512
#define T_SZ 1024
#define NH   8
#define DK   64

// 1/sqrt(d_k) * 1/ln(2): folded into Q projection; softmax runs in exp2 domain
#define QSCL 0.18033688f

__device__ __forceinline__ u16 f2bf(float f) {
  u32 u = __float_as_uint(f);
  u = u + 0x7fffu + ((u >> 16) & 1u);   // RNE
  return (u16)(u >> 16);
}

// single v_exp_f32 (exp2f libm path is ~10 instrs — measured VALU regression r4)
__device__ __forceinline__ float fexp2(float x) {
  return __builtin_amdgcn_exp2f(x);
}

__device__ __forceinline__ u32 cvtpk(float lo, float hi) {
  u32 r;
  asm("v_cvt_pk_bf16_f32 %0, %1, %2" : "=v"(r) : "v"(lo), "v"(hi));
  return r;
}

__device__ __forceinline__ void permswap(u32 &a, u32 &b) {
  asm volatile("v_permlane32_swap_b32 %0, %1" : "+v"(a), "+v"(b));
}

// async global->LDS, 16B per lane; LDS dest is wave-uniform base + lane*16
__device__ __forceinline__ void gload16(const u16* g, u16* l) {
  __builtin_amdgcn_global_load_lds(
      (const __attribute__((address_space(1))) void*)g,
      (__attribute__((address_space(3))) void*)l, 16, 0, 0);
}

// ---- merged: W' = W * inv (bf16); b' = b*inv + beta - mean*inv -----------
__global__ void prep_wb(const float* __restrict__ Ws, const float* __restrict__ bs,
                        const float* __restrict__ gam, const float* __restrict__ beta,
                        const float* __restrict__ mean, const float* __restrict__ var,
                        u16* __restrict__ Wp, float* __restrict__ bp) {
  int bx = blockIdx.x;
  if (bx < 4096) {
    int idx = bx * 256 + threadIdx.x;            // 4*512*512
    int io = idx >> 9;                           // i*512 + o
    float inv = gam[io] * rsqrtf(var[io] + 1e-5f);
    Wp[idx] = f2bf(Ws[idx] * inv);
  } else {
    int idx = (bx - 4096) * 256 + threadIdx.x;   // 2048
    float inv = gam[idx] * rsqrtf(var[idx] + 1e-5f);
    bp[idx] = bs[idx] * inv + beta[idx] - mean[idx] * inv;
  }
}

// ---- in[b][c][t] f32 -> Xt[src][b][t][c] bf16; k,v also copied to cache --
__global__ void transpose_cvt(const float* __restrict__ q, const float* __restrict__ k,
                              const float* __restrict__ v, u16* __restrict__ Xt,
                              float* __restrict__ cache) {
  __shared__ float tile[32][33];
  int z = blockIdx.z;
  int src = z >> 3, b = z & 7;
  const float* in = (src == 0) ? q : ((src == 1) ? k : v);
  u16* out = Xt + (size_t)src * ((size_t)B_SZ * T_SZ * C_SZ);
  int t0 = blockIdx.x * 32, c0 = blockIdx.y * 32;
  int tx = threadIdx.x & 31, ty = threadIdx.x >> 5;
#pragma unroll
  for (int rr = 0; rr < 4; ++rr) {
    int c = c0 + ty + rr * 8;
    float val = in[(((size_t)b * C_SZ + c) << 10) + t0 + tx];
    tile[ty + rr * 8][tx] = val;
    if (src >= 1) {   // cache = concat(key, value) along channel dim
      int cc = c + (src == 2 ? 512 : 0);
      cache[((size_t)b << 20) + ((size_t)cc << 10) + t0 + tx] = val;
    }
  }
  __syncthreads();
#pragma unroll
  for (int rr = 0; rr < 4; ++rr) {
    int t = t0 + ty + rr * 8;
    out[(((size_t)b << 10) + t) * C_SZ + c0 + tx] = f2bf(tile[tx][ty + rr * 8]);
  }
}

// ---- mask (B,1,T,T) int32 -> bit-plane mbT[b][s/32][t] -------------------
__global__ void mask_bits(const int* __restrict__ mask, u32* __restrict__ mbT) {
  int w = blockIdx.x * 256 + threadIdx.x;        // 262144
  int bt = w >> 5;                               // b*1024 + t
  int st = w & 31;
  const int* mrow = mask + ((size_t)bt << 10) + (st << 5);
  u32 word = 0;
#pragma unroll
  for (int j = 0; j < 32; j += 4) {
    int4 m4 = *(const int4*)(mrow + j);
    word |= (m4.x != 0 ? 1u : 0u) << j;
    word |= (m4.y != 0 ? 1u : 0u) << (j + 1);
    word |= (m4.z != 0 ? 1u : 0u) << (j + 2);
    word |= (m4.w != 0 ? 1u : 0u) << (j + 3);
  }
  int b = bt >> 10, t = bt & 1023;
  mbT[(((size_t)b * 32 + st) << 10) + t] = word;
}

// ---- fused QKV projection GEMM (one dispatch, 768 blocks = 3/CU) ---------
// src = blockIdx.z>>3: 0->Qf (scaled by QSCL), 1->Kf, 2->Vf fragment layouts
// K-loop: reg-prefetch pipeline (load kt+1 under compute kt) + XOR-swizzled LDS
__launch_bounds__(256, 4)
__global__ void gemm_qkv(const u16* __restrict__ Wp, const float* __restrict__ bpA,
                         const u16* __restrict__ Xt,
                         u16* __restrict__ Qf, u16* __restrict__ Kf, u16* __restrict__ Vf) {
  __shared__ __align__(16) u16 lds[2 * 128 * 64];
  int tid = threadIdx.x;
  int src = blockIdx.z >> 3;
  int b   = blockIdx.z & 7;
  int t0 = blockIdx.x * 128;
  int o0 = blockIdx.y * 128;
  int wid = tid >> 6, lane = tid & 63;
  int ln = lane & 31, hi = lane >> 5;
  int wr = wid >> 1, wc = wid & 1;

  const u16* Wsrc = Wp + (size_t)src * 262144;
  const float* bp = bpA + src * 512;
  const u16* Xin  = Xt + (size_t)src * ((size_t)B_SZ * T_SZ * C_SZ);
  u16* Yout = (src == 0) ? Qf : (src == 1 ? Kf : Vf);

  const char* Ag = (const char*)Wsrc;                                    // rows: o (1024 B stride)
  const char* Bg = (const char*)(Xin + (((size_t)b << 10) + t0) * C_SZ); // rows: t-local
  char* ldsA = (char*)lds;
  char* ldsB = (char*)lds + 16384;

  accfrag acc[2][2];
#pragma unroll
  for (int m2 = 0; m2 < 2; ++m2)
#pragma unroll
    for (int n2 = 0; n2 < 2; ++n2)
#pragma unroll
      for (int e = 0; e < 16; ++e) acc[m2][n2][e] = 0.f;

  int lin = tid * 16;
  u32x4 ra[4], rb[4];
#pragma unroll
  for (int it = 0; it < 4; ++it) {   // prologue: load kt=0
    int off = lin + it * 4096;
    int r = off >> 7, cb = off & 127;
    ra[it] = *(const u32x4*)(Ag + (size_t)(o0 + r) * 1024 + cb);
    rb[it] = *(const u32x4*)(Bg + (size_t)r * 1024 + cb);
  }

  for (int kt = 0; kt < 8; ++kt) {
    __syncthreads();   // LDS free (previous compute done by all waves)
#pragma unroll
    for (int it = 0; it < 4; ++it) {
      int off = lin + it * 4096;
      int swz = off ^ (((off >> 7) & 7) << 4);   // bank swizzle (G4)
      *(u32x4*)(ldsA + swz) = ra[it];
      *(u32x4*)(ldsB + swz) = rb[it];
    }
    __syncthreads();   // LDS ready
    if (kt < 7) {      // prefetch kt+1; latency hides under the MFMA cluster
#pragma unroll
      for (int it = 0; it < 4; ++it) {
        int off = lin + it * 4096;
        int r = off >> 7, cb = off & 127;
        ra[it] = *(const u32x4*)(Ag + (size_t)(o0 + r) * 1024 + (kt + 1) * 128 + cb);
        rb[it] = *(const u32x4*)(Bg + (size_t)r * 1024 + (kt + 1) * 128 + cb);
      }
    }
#pragma unroll
    for (int kk = 0; kk < 4; ++kk) {
      int csw = (kk * 32 + hi * 16) ^ ((ln & 7) << 4);   // swizzled col
      bfrag a[2], bb[2];
#pragma unroll
      for (int m2 = 0; m2 < 2; ++m2)
        a[m2] = *(const bfrag*)(ldsA + (wr * 64 + m2 * 32 + ln) * 128 + csw);
#pragma unroll
      for (int n2 = 0; n2 < 2; ++n2)
        bb[n2] = *(const bfrag*)(ldsB + (wc * 64 + n2 * 32 + ln) * 128 + csw);
#pragma unroll
      for (int m2 = 0; m2 < 2; ++m2)
#pragma unroll
        for (int n2 = 0; n2 < 2; ++n2)
          acc[m2][n2] = __builtin_amdgcn_mfma_f32_32x32x16_bf16(a[m2], bb[n2], acc[m2][n2], 0, 0, 0);
    }
  }

  float oscl = (src == 0) ? QSCL : 1.0f;
#pragma unroll
  for (int m2 = 0; m2 < 2; ++m2) {
    int obase = o0 + wr * 64 + m2 * 32;
#pragma unroll
    for (int n2 = 0; n2 < 2; ++n2) {
      int t = t0 + wc * 64 + n2 * 32 + ln;
      if (src < 2) {
        // Q/K fragment layout: [(b*8+h)*32 + t/32][dd>>4][(t&31)+32*((dd>>3)&1)][dd&7]
        int tt5 = t & 31, st = t >> 5;
#pragma unroll
        for (int g = 0; g < 4; ++g) {
          int d0 = obase + 8 * g + 4 * hi;
          int hh = d0 >> 6, dd = d0 & 63;
          u16x4 pk4;
#pragma unroll
          for (int qq = 0; qq < 4; ++qq)
            pk4[qq] = f2bf((acc[m2][n2][4 * g + qq] + bp[d0 + qq]) * oscl);
          size_t a = ((((size_t)b * 8 + hh) * 32 + st) << 11)
                   + (size_t)((dd >> 4) * 512 + (tt5 + 32 * ((dd >> 3) & 1)) * 8 + (dd & 7));
          *(u16x4*)(Yout + a) = pk4;
        }
      } else {
        // V-fragment layout: fi=((s>>4)&1)*2+((dd>>5)&1), l=(dd&31)+((s>>3)&1)*32
        int s = t, st = s >> 5;
#pragma unroll
        for (int r = 0; r < 16; ++r) {
          int d = obase + (r & 3) + 8 * (r >> 2) + 4 * hi;
          int hh = d >> 6, dd = d & 63;
          int fi = ((s >> 4) & 1) * 2 + ((dd >> 5) & 1);
          int l  = (dd & 31) + ((s >> 3) & 1) * 32;
          Yout[((((size_t)b * 8 + hh) * 32 + st) << 11)
               + (size_t)(fi * 512 + l * 8 + (s & 7))] = f2bf(acc[m2][n2][r] + bp[d]);
        }
      }
    }
  }
}

// ---- out projection GEMM: f32 natural [b][c][t] --------------------------
// 128(o) x 64(t) tiles -> 512 blocks = 2/CU. Reg-prefetch + swizzle; LDS 24KB.
__launch_bounds__(256, 4)
__global__ void gemm_out(const u16* __restrict__ Wp, const float* __restrict__ bp,
                         const u16* __restrict__ Xin, float* __restrict__ Yout) {
  __shared__ __align__(16) char ldsc[24576];   // A 16KB | B 8KB
  int tid = threadIdx.x;
  int b  = blockIdx.z;
  int t0 = blockIdx.x * 64;
  int o0 = blockIdx.y * 128;
  int wid = tid >> 6, lane = tid & 63;
  int ln = lane & 31, hi = lane >> 5;
  int wr = wid >> 1, wc = wid & 1;

  const char* Ag = (const char*)Wp;                                      // rows: o
  const char* Bg = (const char*)(Xin + (((size_t)b << 10) + t0) * C_SZ); // rows: t-local
  char* ldsA = ldsc;
  char* ldsB = ldsc + 16384;

  accfrag acc[2];
#pragma unroll
  for (int m2 = 0; m2 < 2; ++m2)
#pragma unroll
    for (int e = 0; e < 16; ++e) acc[m2][e] = 0.f;

  int lin = tid * 16;
  u32x4 ra[4], rb[2];
#pragma unroll
  for (int it = 0; it < 4; ++it) {
    int off = lin + it * 4096;
    int r = off >> 7, cb = off & 127;
    ra[it] = *(const u32x4*)(Ag + (size_t)(o0 + r) * 1024 + cb);
  }
#pragma unroll
  for (int it = 0; it < 2; ++it) {
    int off = lin + it * 4096;
    int r = off >> 7, cb = off & 127;
    rb[it] = *(const u32x4*)(Bg + (size_t)r * 1024 + cb);
  }

  for (int kt = 0; kt < 8; ++kt) {
    __syncthreads();
#pragma unroll
    for (int it = 0; it < 4; ++it) {
      int off = lin + it * 4096;
      int swz = off ^ (((off >> 7) & 7) << 4);
      *(u32x4*)(ldsA + swz) = ra[it];
    }
#pragma unroll
    for (int it = 0; it < 2; ++it) {
      int off = lin + it * 4096;
      int swz = off ^ (((off >> 7) & 7) << 4);
      *(u32x4*)(ldsB + swz) = rb[it];
    }
    __syncthreads();
    if (kt < 7) {
#pragma unroll
      for (int it = 0; it < 4; ++it) {
        int off = lin + it * 4096;
        int r = off >> 7, cb = off & 127;
        ra[it] = *(const u32x4*)(Ag + (size_t)(o0 + r) * 1024 + (kt + 1) * 128 + cb);
      }
#pragma unroll
      for (int it = 0; it < 2; ++it) {
        int off = lin + it * 4096;
        int r = off >> 7, cb = off & 127;
        rb[it] = *(const u32x4*)(Bg + (size_t)r * 1024 + (kt + 1) * 128 + cb);
      }
    }
#pragma unroll
    for (int kk = 0; kk < 4; ++kk) {
      int csw = (kk * 32 + hi * 16) ^ ((ln & 7) << 4);
      bfrag a[2], bb;
#pragma unroll
      for (int m2 = 0; m2 < 2; ++m2)
        a[m2] = *(const bfrag*)(ldsA + (wr * 64 + m2 * 32 + ln) * 128 + csw);
      bb = *(const bfrag*)(ldsB + (wc * 32 + ln) * 128 + csw);
#pragma unroll
      for (int m2 = 0; m2 < 2; ++m2)
        acc[m2] = __builtin_amdgcn_mfma_f32_32x32x16_bf16(a[m2], bb, acc[m2], 0, 0, 0);
    }
  }

#pragma unroll
  for (int m2 = 0; m2 < 2; ++m2) {
    int obase = o0 + wr * 64 + m2 * 32;
    int t = t0 + wc * 32 + ln;
#pragma unroll
    for (int r = 0; r < 16; ++r) {
      int o = obase + (r & 3) + 8 * (r >> 2) + 4 * hi;
      Yout[(((size_t)b * C_SZ + o) << 10) + t] = acc[m2][r] + bp[o];
    }
  }
}

// ---- fused flash attention, 4-way s-split, single-buffer read-early ------
// 1024 blocks x 512 thr: 4 s-groups x 2 q-tiles. Per iter: read LDS frags to
// regs -> barrier -> DMA next tile into SAME buffer -> compute from regs ->
// barrier(drain). launch_bounds(512,4): r10's (512,8) capped VGPR at 64 ->
// full scratch spill (VGPR 32, 1.5GB HBM traffic, 327us). 128-cap = no spill.
__launch_bounds__(512, 4)
__global__ void attn_fused(const u16* __restrict__ Qf, const u16* __restrict__ Kf,
                           const u16* __restrict__ Vf, const u32* __restrict__ mbT,
                           u16* __restrict__ X2) {
  __shared__ __align__(16) char smem[34816];  // 32KB stage/merge + 2KB m/l
  float* mlb = (float*)(smem + 32768);        // [slot:8][ln:32][2] f32

  int n = blockIdx.x;
  int bh = n & 63, tb = n >> 6;               // tb 0..15
  int b = bh >> 3, h = bh & 7;
  int tid = threadIdx.x;
  int wid = tid >> 6, lane = tid & 63;
  int grp = wid >> 1, wl = wid & 1;           // grp 0..3 (s-quarter), wl 0..1 (q-tile)
  int ln = lane & 31, hi = lane >> 5;
  int tt = tb * 2 + wl;                       // q-tile 0..31
  int t  = tt * 32 + ln;

  // Q fragments: one coalesced 1KB load per j
  const u16* QfT = Qf + (((size_t)bh * 32 + tt) << 11);
  bfrag qf[4];
#pragma unroll
  for (int j = 0; j < 4; ++j)
    qf[j] = *(const bfrag*)(QfT + j * 512 + lane * 8);

  const u16* KfB = Kf + ((size_t)bh << 16);
  const u16* VfB = Vf + ((size_t)bh << 16);
  const u32* mcol = mbT + ((size_t)b << 15) + t;

  // m_run floor -1e4: masked scores stay -1e30 -> exp2(-1e30-m) == +0 in HW.
  float m_run = -1.0e4f, l_run = 0.f;
  accfrag accd[2];
#pragma unroll
  for (int m2 = 0; m2 < 2; ++m2)
#pragma unroll
    for (int e = 0; e < 16; ++e) accd[m2][e] = 0.f;

  int gid = tid & 127;                        // thread id within group (2 waves)
  u16* sK = (u16*)smem + grp * 4096;          // 4KB K + 4KB V per group
  u16* sV = sK + 2048;
  int st0 = grp * 8;

  // prologue: stage tile st0, load mask word
  {
    size_t tn = (size_t)st0 << 11;
    gload16(KfB + tn + gid * 8,        sK + gid * 8);
    gload16(KfB + tn + 1024 + gid * 8, sK + 1024 + gid * 8);
    gload16(VfB + tn + gid * 8,        sV + gid * 8);
    gload16(VfB + tn + 1024 + gid * 8, sV + 1024 + gid * 8);
  }
  u32 mw = mcol[st0 << 10];
  __syncthreads();                            // tile 0 DMA drained

  for (int it = 0; it < 8; ++it) {
    int st = st0 + it;

    // 1) LDS -> regs (lane-linear, conflict-free b128)
    bfrag kf[4], vf[4];
#pragma unroll
    for (int j = 0; j < 4; ++j) {
      kf[j] = *(const bfrag*)(sK + j * 512 + lane * 8);
      vf[j] = *(const bfrag*)(sV + j * 512 + lane * 8);
    }
    __syncthreads();                          // all reads done; buffer free

    // 2) DMA next tile into the same buffer; hides under compute below
    u32 mn = 0;
    if (it < 7) {
      size_t tn = (size_t)(st + 1) << 11;
      gload16(KfB + tn + gid * 8,        sK + gid * 8);
      gload16(KfB + tn + 1024 + gid * 8, sK + 1024 + gid * 8);
      gload16(VfB + tn + gid * 8,        sV + gid * 8);
      gload16(VfB + tn + 1024 + gid * 8, sV + 1024 + gid * 8);
      mn = mcol[(st + 1) << 10];
    }

    // 3) QK^T (S already in log2 units: Q pre-scaled)
    accfrag S;
#pragma unroll
    for (int e = 0; e < 16; ++e) S[e] = 0.f;
    __builtin_amdgcn_s_setprio(1);
#pragma unroll
    for (int j = 0; j < 4; ++j)
      S = __builtin_amdgcn_mfma_f32_32x32x16_bf16(kf[j], qf[j], S, 0, 0, 0);
    __builtin_amdgcn_s_setprio(0);

    // ---- softmax over key rows (per-lane: 16 of 32 rows; partner lane^32)
    u32 mbits = mw >> (4 * hi);
    float p[16];
#pragma unroll
    for (int r = 0; r < 16; ++r) {
      int pos = (r & 3) + 8 * (r >> 2);
      p[r] = ((mbits >> pos) & 1u) ? S[r] : -1e30f;
    }
    float q8[8], q4[4];
#pragma unroll
    for (int r = 0; r < 8; ++r) q8[r] = fmaxf(p[r], p[r + 8]);
#pragma unroll
    for (int r = 0; r < 4; ++r) q4[r] = fmaxf(q8[r], q8[r + 4]);
    float pmax = fmaxf(fmaxf(q4[0], q4[1]), fmaxf(q4[2], q4[3]));
    pmax = fmaxf(pmax, __shfl_xor(pmax, 32));

    // deferred rescale (T13): 8 nats = 11.54 bits
    if (__any(pmax > m_run + 11.5f)) {
      float m_new = fmaxf(m_run, pmax);
      float alpha = fexp2(m_run - m_new);
      l_run *= alpha;
#pragma unroll
      for (int m2 = 0; m2 < 2; ++m2)
#pragma unroll
        for (int e = 0; e < 16; ++e) accd[m2][e] *= alpha;
      m_run = m_new;
    }

#pragma unroll
    for (int r = 0; r < 16; ++r)
      p[r] = fexp2(p[r] - m_run);             // masked: exp2(-1e30) == +0
    float s8[8], s4[4];
#pragma unroll
    for (int r = 0; r < 8; ++r) s8[r] = p[r] + p[r + 8];
#pragma unroll
    for (int r = 0; r < 4; ++r) s4[r] = s8[r] + s8[r + 4];
    float psum = (s4[0] + s4[1]) + (s4[2] + s4[3]);
    psum += __shfl_xor(psum, 32);
    l_run += psum;

    // P (D-layout) -> B-operand bf16 frags: 8 cvt_pk + 4 permlane32_swap
    bfrag pf[2];
#pragma unroll
    for (int j2 = 0; j2 < 2; ++j2) {
      u32 A0 = cvtpk(p[8 * j2 + 0], p[8 * j2 + 1]);
      u32 A1 = cvtpk(p[8 * j2 + 2], p[8 * j2 + 3]);
      u32 B0 = cvtpk(p[8 * j2 + 4], p[8 * j2 + 5]);
      u32 B1 = cvtpk(p[8 * j2 + 6], p[8 * j2 + 7]);
      permswap(A0, B0);
      permswap(A1, B1);
      union { u32 u[4]; bfrag f; } pu;
      pu.u[0] = A0; pu.u[1] = A1; pu.u[2] = B0; pu.u[3] = B1;
      pf[j2] = pu.f;
    }
    __builtin_amdgcn_s_setprio(1);
#pragma unroll
    for (int j2 = 0; j2 < 2; ++j2)
#pragma unroll
      for (int m2 = 0; m2 < 2; ++m2)
        accd[m2] = __builtin_amdgcn_mfma_f32_32x32x16_bf16(vf[j2 * 2 + m2], pf[j2], accd[m2], 0, 0, 0);
    __builtin_amdgcn_s_setprio(0);

    __syncthreads();                          // drains next-tile DMA
    mw = mn;
  }

  // ---- 4-way merge through LDS (reusing the 32KB stage region) ----------
  float* comb = (float*)smem;
  // (last loop barrier already passed; stage region free)
  // Round 1: grps 1,3 publish; grps 0,2 absorb
  if (grp & 1) {
    float* dst = comb + ((grp >> 1) * 4096 + wl * 2048);
#pragma unroll
    for (int m2 = 0; m2 < 2; ++m2)
#pragma unroll
      for (int e = 0; e < 16; ++e)
        dst[(m2 * 16 + e) * 64 + lane] = accd[m2][e];
    if (hi == 0) {
      mlb[((grp * 2 + wl) * 32 + ln) * 2]     = m_run;
      mlb[((grp * 2 + wl) * 32 + ln) * 2 + 1] = l_run;
    }
  }
  __syncthreads();
  if (!(grp & 1)) {
    int pg = grp + 1;
    const float* srcp = comb + ((pg >> 1) * 4096 + wl * 2048);
    float m1 = mlb[((pg * 2 + wl) * 32 + ln) * 2];
    float l1 = mlb[((pg * 2 + wl) * 32 + ln) * 2 + 1];
    float M  = fmaxf(m_run, m1);
    float w0 = fexp2(m_run - M), w1 = fexp2(m1 - M);
    l_run = l_run * w0 + l1 * w1;
    m_run = M;
#pragma unroll
    for (int m2 = 0; m2 < 2; ++m2)
#pragma unroll
      for (int e = 0; e < 16; ++e)
        accd[m2][e] = accd[m2][e] * w0 + srcp[(m2 * 16 + e) * 64 + lane] * w1;
  }
  __syncthreads();
  // Round 2: grp 2 publishes; grp 0 absorbs + writes out
  if (grp == 2) {
    float* dst = comb + wl * 2048;
#pragma unroll
    for (int m2 = 0; m2 < 2; ++m2)
#pragma unroll
      for (int e = 0; e < 16; ++e)
        dst[(m2 * 16 + e) * 64 + lane] = accd[m2][e];
    if (hi == 0) {
      mlb[((4 + wl) * 32 + ln) * 2]     = m_run;
      mlb[((4 + wl) * 32 + ln) * 2 + 1] = l_run;
    }
  }
  __syncthreads();
  if (grp == 0) {
    const float* srcp = comb + wl * 2048;
    float m1 = mlb[((4 + wl) * 32 + ln) * 2];
    float l1 = mlb[((4 + wl) * 32 + ln) * 2 + 1];
    float M  = fmaxf(m_run, m1);
    float w0 = fexp2(m_run - M), w1 = fexp2(m1 - M);
    float l  = l_run * w0 + l1 * w1;
    float invl = (l > 0.f) ? 1.f / l : 0.f;
    u16* Orow = X2 + (((size_t)b << 10) + t) * C_SZ + h * DK;
#pragma unroll
    for (int m2 = 0; m2 < 2; ++m2)
#pragma unroll
      for (int g = 0; g < 4; ++g) {
        u16x4 pk4;
#pragma unroll
        for (int qq = 0; qq < 4; ++qq) {
          int e = 4 * g + qq;
          float v2 = srcp[(m2 * 16 + e) * 64 + lane];
          pk4[qq] = f2bf((accd[m2][e] * w0 + v2 * w1) * invl);
        }
        *(u16x4*)(Orow + m2 * 32 + 8 * g + 4 * hi) = pk4;
      }
  }
}

extern "C" void kernel_launch(void* const* d_in, const int* in_sizes, int n_in,
                              void* d_out, int out_size, void* d_ws, size_t ws_size,
                              hipStream_t stream) {
  (void)in_sizes; (void)n_in; (void)out_size; (void)ws_size;
  const float* q    = (const float*)d_in[0];
  const float* k    = (const float*)d_in[1];
  const float* v    = (const float*)d_in[2];
  const int*   mask = (const int*)d_in[3];
  const float* Ws   = (const float*)d_in[4];
  const float* bs   = (const float*)d_in[5];
  const float* gam  = (const float*)d_in[6];
  const float* beta = (const float*)d_in[7];
  const float* mean = (const float*)d_in[8];
  const float* var  = (const float*)d_in[9];

  float* out   = (float*)d_out;
  float* cache = out + (size_t)B_SZ * C_SZ * T_SZ;     // 4,194,304 floats

  const size_t ARR = (size_t)B_SZ * T_SZ * C_SZ;       // 4,194,304 elems
  char* ws = (char*)d_ws;
  u16*   Wp = (u16*)(ws);                              // 4*512*512 bf16 = 2 MB
  float* bp = (float*)(ws + 2097152);                  // 2048 f32
  u16*   Xt = (u16*)(ws + 2162688);                    // 3 * ARR bf16
  u16*   Qt = Xt + 3 * ARR;                            // Qf fragment layout
  u16*   Kt = Qt + ARR;                                // Kf fragment layout
  u16*   Vb = Kt + ARR;                                // Vf fragment layout
  u16*   X2 = Vb + ARR;
  u32*   mb = (u32*)((char*)(X2 + ARR));               // 262144 words = 1 MB

  prep_wb<<<4104, 256, 0, stream>>>(Ws, bs, gam, beta, mean, var, Wp, bp);
  transpose_cvt<<<dim3(32, 16, 24), 256, 0, stream>>>(q, k, v, Xt, cache);
  mask_bits<<<1024, 256, 0, stream>>>(mask, mb);

  gemm_qkv<<<dim3(8, 4, 24), 256, 0, stream>>>(Wp, bp, Xt, Qt, Kt, Vb);
  attn_fused<<<1024, 512, 0, stream>>>(Qt, Kt, Vb, mb, X2);
  gemm_out<<<dim3(16, 4, 8), 256, 0, stream>>>(Wp + 786432, bp + 1536, X2, out);
}

// Round 12
// 99.248 us; speedup vs baseline: 4.0314x; 1.0075x over previous
//
#include <hip/hip_runtime.h>

typedef unsigned short u16;
typedef unsigned int   u32;
typedef short  bfrag   __attribute__((ext_vector_type(8)));   // 8 bf16 = 4 VGPR
typedef float  accfrag __attribute__((ext_vector_type(16)));  // 32x32 C/D
typedef unsigned int   u32x4 __attribute__((ext_vector_type(4)));
typedef unsigned short u16x4 __attribute__((ext_vector_type(4)));
typedef float          f32x4 __attribute__((ext_vector_type(4)));

#define B_SZ 8
#define C_SZ 512
#define T_SZ 1024
#define NH   8
#define DK   64

// 1/sqrt(d_k) * 1/ln(2): folded into Q projection; softmax runs in exp2 domain
#define QSCL 0.18033688f

__device__ __forceinline__ u16 f2bf(float f) {
  u32 u = __float_as_uint(f);
  u = u + 0x7fffu + ((u >> 16) & 1u);   // RNE
  return (u16)(u >> 16);
}

// single v_exp_f32 (exp2f libm path is ~10 instrs — measured VALU regression r4)
__device__ __forceinline__ float fexp2(float x) {
  return __builtin_amdgcn_exp2f(x);
}

__device__ __forceinline__ u32 cvtpk(float lo, float hi) {
  u32 r;
  asm("v_cvt_pk_bf16_f32 %0, %1, %2" : "=v"(r) : "v"(lo), "v"(hi));
  return r;
}

__device__ __forceinline__ void permswap(u32 &a, u32 &b) {
  asm volatile("v_permlane32_swap_b32 %0, %1" : "+v"(a), "+v"(b));
}

// async global->LDS, 16B per lane; LDS dest is wave-uniform base + lane*16
__device__ __forceinline__ void gload16(const u16* g, u16* l) {
  __builtin_amdgcn_global_load_lds(
      (const __attribute__((address_space(1))) void*)g,
      (__attribute__((address_space(3))) void*)l, 16, 0, 0);
}

// ---- fused prologue: transpose_cvt (bx<12288) | prep_wb | mask_bits ------
// All three are independent memory-bound prep ops; one dispatch saves 2
// launch gaps and overlaps their tails.
__global__ void prologue(const float* __restrict__ q, const float* __restrict__ k,
                         const float* __restrict__ v, const int* __restrict__ mask,
                         const float* __restrict__ Ws, const float* __restrict__ bs,
                         const float* __restrict__ gam, const float* __restrict__ beta,
                         const float* __restrict__ mean, const float* __restrict__ var,
                         u16* __restrict__ Xt, float* __restrict__ cache,
                         u16* __restrict__ Wp, float* __restrict__ bp,
                         u32* __restrict__ mbT) {
  __shared__ float tile[32][33];
  int bx = blockIdx.x;
  if (bx < 12288) {
    // ---- in[b][c][t] f32 -> Xt[src][b][t][c] bf16; k,v also -> cache ----
    int z = bx >> 9;                 // 0..23
    int rem = bx & 511;
    int t0 = (rem & 31) * 32, c0 = (rem >> 5) * 32;
    int src = z >> 3, b = z & 7;
    const float* in = (src == 0) ? q : ((src == 1) ? k : v);
    u16* out = Xt + (size_t)src * ((size_t)B_SZ * T_SZ * C_SZ);
    int tx = threadIdx.x & 31, ty = threadIdx.x >> 5;
#pragma unroll
    for (int rr = 0; rr < 4; ++rr) {
      int c = c0 + ty + rr * 8;
      float val = in[(((size_t)b * C_SZ + c) << 10) + t0 + tx];
      tile[ty + rr * 8][tx] = val;
      if (src >= 1) {   // cache = concat(key, value) along channel dim
        int cc = c + (src == 2 ? 512 : 0);
        cache[((size_t)b << 20) + ((size_t)cc << 10) + t0 + tx] = val;
      }
    }
    __syncthreads();
#pragma unroll
    for (int rr = 0; rr < 4; ++rr) {
      int t = t0 + ty + rr * 8;
      out[(((size_t)b << 10) + t) * C_SZ + c0 + tx] = f2bf(tile[tx][ty + rr * 8]);
    }
  } else if (bx < 16392) {
    // ---- W' = W*inv (bf16); b' = b*inv + beta - mean*inv ----
    int bb = bx - 12288;
    if (bb < 4096) {
      int idx = bb * 256 + threadIdx.x;            // 4*512*512
      int io = idx >> 9;
      float inv = gam[io] * rsqrtf(var[io] + 1e-5f);
      Wp[idx] = f2bf(Ws[idx] * inv);
    } else {
      int idx = (bb - 4096) * 256 + threadIdx.x;   // 2048
      float inv = gam[idx] * rsqrtf(var[idx] + 1e-5f);
      bp[idx] = bs[idx] * inv + beta[idx] - mean[idx] * inv;
    }
  } else {
    // ---- mask (B,1,T,T) int32 -> bit-plane mbT[b][s/32][t]; 2 words/thr --
    int w0 = (bx - 16392) * 512 + threadIdx.x;
#pragma unroll
    for (int half = 0; half < 2; ++half) {
      int w = w0 + half * 256;
      int bt = w >> 5;
      int st = w & 31;
      const int* mrow = mask + ((size_t)bt << 10) + (st << 5);
      u32 word = 0;
#pragma unroll
      for (int j = 0; j < 32; j += 4) {
        int4 m4 = *(const int4*)(mrow + j);
        word |= (m4.x != 0 ? 1u : 0u) << j;
        word |= (m4.y != 0 ? 1u : 0u) << (j + 1);
        word |= (m4.z != 0 ? 1u : 0u) << (j + 2);
        word |= (m4.w != 0 ? 1u : 0u) << (j + 3);
      }
      int b = bt >> 10, t = bt & 1023;
      mbT[(((size_t)b * 32 + st) << 10) + t] = word;
    }
  }
}

// ---- fused QKV projection GEMM (one dispatch, 768 blocks = 3/CU) ---------
// src = blockIdx.z>>3: 0->Qf (scaled by QSCL), 1->Kf, 2->Vf fragment layouts
// K-loop: reg-prefetch pipeline (load kt+1 under compute kt) + XOR-swizzled LDS
__launch_bounds__(256, 4)
__global__ void gemm_qkv(const u16* __restrict__ Wp, const float* __restrict__ bpA,
                         const u16* __restrict__ Xt,
                         u16* __restrict__ Qf, u16* __restrict__ Kf, u16* __restrict__ Vf) {
  __shared__ __align__(16) u16 lds[2 * 128 * 64];
  int tid = threadIdx.x;
  int src = blockIdx.z >> 3;
  int b   = blockIdx.z & 7;
  int t0 = blockIdx.x * 128;
  int o0 = blockIdx.y * 128;
  int wid = tid >> 6, lane = tid & 63;
  int ln = lane & 31, hi = lane >> 5;
  int wr = wid >> 1, wc = wid & 1;

  const u16* Wsrc = Wp + (size_t)src * 262144;
  const float* bp = bpA + src * 512;
  const u16* Xin  = Xt + (size_t)src * ((size_t)B_SZ * T_SZ * C_SZ);
  u16* Yout = (src == 0) ? Qf : (src == 1 ? Kf : Vf);

  const char* Ag = (const char*)Wsrc;                                    // rows: o (1024 B stride)
  const char* Bg = (const char*)(Xin + (((size_t)b << 10) + t0) * C_SZ); // rows: t-local
  char* ldsA = (char*)lds;
  char* ldsB = (char*)lds + 16384;

  accfrag acc[2][2];
#pragma unroll
  for (int m2 = 0; m2 < 2; ++m2)
#pragma unroll
    for (int n2 = 0; n2 < 2; ++n2)
#pragma unroll
      for (int e = 0; e < 16; ++e) acc[m2][n2][e] = 0.f;

  int lin = tid * 16;
  u32x4 ra[4], rb[4];
#pragma unroll
  for (int it = 0; it < 4; ++it) {   // prologue: load kt=0
    int off = lin + it * 4096;
    int r = off >> 7, cb = off & 127;
    ra[it] = *(const u32x4*)(Ag + (size_t)(o0 + r) * 1024 + cb);
    rb[it] = *(const u32x4*)(Bg + (size_t)r * 1024 + cb);
  }

  for (int kt = 0; kt < 8; ++kt) {
    __syncthreads();   // LDS free (previous compute done by all waves)
#pragma unroll
    for (int it = 0; it < 4; ++it) {
      int off = lin + it * 4096;
      int swz = off ^ (((off >> 7) & 7) << 4);   // bank swizzle (G4)
      *(u32x4*)(ldsA + swz) = ra[it];
      *(u32x4*)(ldsB + swz) = rb[it];
    }
    __syncthreads();   // LDS ready
    if (kt < 7) {      // prefetch kt+1; latency hides under the MFMA cluster
#pragma unroll
      for (int it = 0; it < 4; ++it) {
        int off = lin + it * 4096;
        int r = off >> 7, cb = off & 127;
        ra[it] = *(const u32x4*)(Ag + (size_t)(o0 + r) * 1024 + (kt + 1) * 128 + cb);
        rb[it] = *(const u32x4*)(Bg + (size_t)r * 1024 + (kt + 1) * 128 + cb);
      }
    }
#pragma unroll
    for (int kk = 0; kk < 4; ++kk) {
      int csw = (kk * 32 + hi * 16) ^ ((ln & 7) << 4);   // swizzled col
      bfrag a[2], bb[2];
#pragma unroll
      for (int m2 = 0; m2 < 2; ++m2)
        a[m2] = *(const bfrag*)(ldsA + (wr * 64 + m2 * 32 + ln) * 128 + csw);
#pragma unroll
      for (int n2 = 0; n2 < 2; ++n2)
        bb[n2] = *(const bfrag*)(ldsB + (wc * 64 + n2 * 32 + ln) * 128 + csw);
#pragma unroll
      for (int m2 = 0; m2 < 2; ++m2)
#pragma unroll
        for (int n2 = 0; n2 < 2; ++n2)
          acc[m2][n2] = __builtin_amdgcn_mfma_f32_32x32x16_bf16(a[m2], bb[n2], acc[m2][n2], 0, 0, 0);
    }
  }

  float oscl = (src == 0) ? QSCL : 1.0f;
#pragma unroll
  for (int m2 = 0; m2 < 2; ++m2) {
    int obase = o0 + wr * 64 + m2 * 32;
#pragma unroll
    for (int n2 = 0; n2 < 2; ++n2) {
      int t = t0 + wc * 64 + n2 * 32 + ln;
      if (src < 2) {
        // Q/K fragment layout: [(b*8+h)*32 + t/32][dd>>4][(t&31)+32*((dd>>3)&1)][dd&7]
        int tt5 = t & 31, st = t >> 5;
#pragma unroll
        for (int g = 0; g < 4; ++g) {
          int d0 = obase + 8 * g + 4 * hi;
          int hh = d0 >> 6, dd = d0 & 63;
          u16x4 pk4;
#pragma unroll
          for (int qq = 0; qq < 4; ++qq)
            pk4[qq] = f2bf((acc[m2][n2][4 * g + qq] + bp[d0 + qq]) * oscl);
          size_t a = ((((size_t)b * 8 + hh) * 32 + st) << 11)
                   + (size_t)((dd >> 4) * 512 + (tt5 + 32 * ((dd >> 3) & 1)) * 8 + (dd & 7));
          *(u16x4*)(Yout + a) = pk4;
        }
      } else {
        // V-fragment layout: fi=((s>>4)&1)*2+((dd>>5)&1), l=(dd&31)+((s>>3)&1)*32
        int s = t, st = s >> 5;
#pragma unroll
        for (int r = 0; r < 16; ++r) {
          int d = obase + (r & 3) + 8 * (r >> 2) + 4 * hi;
          int hh = d >> 6, dd = d & 63;
          int fi = ((s >> 4) & 1) * 2 + ((dd >> 5) & 1);
          int l  = (dd & 31) + ((s >> 3) & 1) * 32;
          Yout[((((size_t)b * 8 + hh) * 32 + st) << 11)
               + (size_t)(fi * 512 + l * 8 + (s & 7))] = f2bf(acc[m2][n2][r] + bp[d]);
        }
      }
    }
  }
}

// ---- out projection GEMM: f32 natural [b][c][t] --------------------------
// 128(o) x 64(t) tiles -> 512 blocks = 2/CU. Reg-prefetch + swizzle; LDS 24KB.
__launch_bounds__(256, 4)
__global__ void gemm_out(const u16* __restrict__ Wp, const float* __restrict__ bp,
                         const u16* __restrict__ Xin, float* __restrict__ Yout) {
  __shared__ __align__(16) char ldsc[24576];   // A 16KB | B 8KB
  int tid = threadIdx.x;
  int b  = blockIdx.z;
  int t0 = blockIdx.x * 64;
  int o0 = blockIdx.y * 128;
  int wid = tid >> 6, lane = tid & 63;
  int ln = lane & 31, hi = lane >> 5;
  int wr = wid >> 1, wc = wid & 1;

  const char* Ag = (const char*)Wp;                                      // rows: o
  const char* Bg = (const char*)(Xin + (((size_t)b << 10) + t0) * C_SZ); // rows: t-local
  char* ldsA = ldsc;
  char* ldsB = ldsc + 16384;

  accfrag acc[2];
#pragma unroll
  for (int m2 = 0; m2 < 2; ++m2)
#pragma unroll
    for (int e = 0; e < 16; ++e) acc[m2][e] = 0.f;

  int lin = tid * 16;
  u32x4 ra[4], rb[2];
#pragma unroll
  for (int it = 0; it < 4; ++it) {
    int off = lin + it * 4096;
    int r = off >> 7, cb = off & 127;
    ra[it] = *(const u32x4*)(Ag + (size_t)(o0 + r) * 1024 + cb);
  }
#pragma unroll
  for (int it = 0; it < 2; ++it) {
    int off = lin + it * 4096;
    int r = off >> 7, cb = off & 127;
    rb[it] = *(const u32x4*)(Bg + (size_t)r * 1024 + cb);
  }

  for (int kt = 0; kt < 8; ++kt) {
    __syncthreads();
#pragma unroll
    for (int it = 0; it < 4; ++it) {
      int off = lin + it * 4096;
      int swz = off ^ (((off >> 7) & 7) << 4);
      *(u32x4*)(ldsA + swz) = ra[it];
    }
#pragma unroll
    for (int it = 0; it < 2; ++it) {
      int off = lin + it * 4096;
      int swz = off ^ (((off >> 7) & 7) << 4);
      *(u32x4*)(ldsB + swz) = rb[it];
    }
    __syncthreads();
    if (kt < 7) {
#pragma unroll
      for (int it = 0; it < 4; ++it) {
        int off = lin + it * 4096;
        int r = off >> 7, cb = off & 127;
        ra[it] = *(const u32x4*)(Ag + (size_t)(o0 + r) * 1024 + (kt + 1) * 128 + cb);
      }
#pragma unroll
      for (int it = 0; it < 2; ++it) {
        int off = lin + it * 4096;
        int r = off >> 7, cb = off & 127;
        rb[it] = *(const u32x4*)(Bg + (size_t)r * 1024 + (kt + 1) * 128 + cb);
      }
    }
#pragma unroll
    for (int kk = 0; kk < 4; ++kk) {
      int csw = (kk * 32 + hi * 16) ^ ((ln & 7) << 4);
      bfrag a[2], bb;
#pragma unroll
      for (int m2 = 0; m2 < 2; ++m2)
        a[m2] = *(const bfrag*)(ldsA + (wr * 64 + m2 * 32 + ln) * 128 + csw);
      bb = *(const bfrag*)(ldsB + (wc * 32 + ln) * 128 + csw);
#pragma unroll
      for (int m2 = 0; m2 < 2; ++m2)
        acc[m2] = __builtin_amdgcn_mfma_f32_32x32x16_bf16(a[m2], bb, acc[m2], 0, 0, 0);
    }
  }

#pragma unroll
  for (int m2 = 0; m2 < 2; ++m2) {
    int obase = o0 + wr * 64 + m2 * 32;
    int t = t0 + wc * 32 + ln;
#pragma unroll
    for (int r = 0; r < 16; ++r) {
      int o = obase + (r & 3) + 8 * (r >> 2) + 4 * hi;
      Yout[(((size_t)b * C_SZ + o) << 10) + t] = acc[m2][r] + bp[o];
    }
  }
}

// ---- fused flash attention (r9 2-way s-split — best measured, LOCKED) ----
// 512 blocks x 512 thr: 2 s-groups x 4 q-tiles. Double-buffered staging:
// DMA next tile issued at top of iter, drained at bottom barrier -> latency
// hides under the whole compute phase. 4-way split falsified twice (r8/r11:
// merge overhead + 2x K/V traffic, no occupancy gain).
__launch_bounds__(512, 4)
__global__ void attn_fused(const u16* __restrict__ Qf, const u16* __restrict__ Kf,
                           const u16* __restrict__ Vf, const u32* __restrict__ mbT,
                           u16* __restrict__ X2) {
  __shared__ __align__(16) char smem[33 * 1024];
  u16*   sK   = (u16*)smem;             // [grp:2][buf:2][2048] = 16 KB
  u16*   sV   = (u16*)(smem + 16384);   // [grp:2][buf:2][2048] = 16 KB
  float* comb = (float*)smem;           // aliases sK/sV post-loop
  float* mlb  = (float*)(smem + 32768); // 4*32*2 f32 = 1 KB

  int n = blockIdx.x;
  int bh = n & 63, tb = n >> 6;
  int b = bh >> 3, h = bh & 7;
  int tid = threadIdx.x;
  int wid = tid >> 6, lane = tid & 63;
  int grp = wid >> 2, wl = wid & 3;
  int ln = lane & 31, hi = lane >> 5;
  int tt = tb * 4 + wl;
  int t  = tt * 32 + ln;

  // Q fragments: one coalesced 1KB load per j
  const u16* QfT = Qf + (((size_t)bh * 32 + tt) << 11);
  bfrag qf[4];
#pragma unroll
  for (int j = 0; j < 4; ++j)
    qf[j] = *(const bfrag*)(QfT + j * 512 + lane * 8);

  const u16* KfB = Kf + ((size_t)bh << 16);
  const u16* VfB = Vf + ((size_t)bh << 16);
  const u32* mcol = mbT + ((size_t)b << 15) + t;

  // m_run floor -1e4: masked scores stay -1e30 -> exp2(-1e30-m) == +0 in HW.
  float m_run = -1.0e4f, l_run = 0.f;
  accfrag accd[2];
#pragma unroll
  for (int m2 = 0; m2 < 2; ++m2)
#pragma unroll
    for (int e = 0; e < 16; ++e) accd[m2][e] = 0.f;

  int gtid = tid & 255;
  int soff = gtid * 8;                      // u16 offset: 16B per thread, per 4-wave group
  u16* sKg = sK + grp * 4096;               // this group's [buf][2048]
  u16* sVg = sV + grp * 4096;
  int st0 = grp * 16;

  // prologue: stage this group's tile 0, load mask word
  gload16(KfB + ((size_t)st0 << 11) + soff, sKg + soff);
  gload16(VfB + ((size_t)st0 << 11) + soff, sVg + soff);
  u32 mw = mcol[st0 << 10];
  __syncthreads();

#pragma unroll 2
  for (int it = 0; it < 16; ++it) {
    int cur = it & 1, nxt = cur ^ 1;
    int st = st0 + it;
    u32 mn = 0;
    if (it < 15) {   // stage next tile; latency spans the whole compute phase
      size_t tn = (size_t)(st + 1) << 11;
      gload16(KfB + tn + soff, sKg + nxt * 2048 + soff);
      gload16(VfB + tn + soff, sVg + nxt * 2048 + soff);
      mn = mcol[(st + 1) << 10];
    }

    // fragments from LDS (lane-linear -> conflict-free b128 reads)
    bfrag kf[4], vf[4];
#pragma unroll
    for (int j = 0; j < 4; ++j) {
      kf[j] = *(const bfrag*)(sKg + cur * 2048 + j * 512 + lane * 8);
      vf[j] = *(const bfrag*)(sVg + cur * 2048 + j * 512 + lane * 8);
    }

    // QK^T (S already in log2 units: Q pre-scaled)
    accfrag S;
#pragma unroll
    for (int e = 0; e < 16; ++e) S[e] = 0.f;
    __builtin_amdgcn_s_setprio(1);
#pragma unroll
    for (int j = 0; j < 4; ++j)
      S = __builtin_amdgcn_mfma_f32_32x32x16_bf16(kf[j], qf[j], S, 0, 0, 0);
    __builtin_amdgcn_s_setprio(0);

    // ---- softmax over key rows (per-lane: 16 of 32 rows; partner lane^32)
    u32 mbits = mw >> (4 * hi);          // bit positions compile-time per r
    float p[16];
#pragma unroll
    for (int r = 0; r < 16; ++r) {
      int pos = (r & 3) + 8 * (r >> 2);  // const -> v_bfe + cndmask
      p[r] = ((mbits >> pos) & 1u) ? S[r] : -1e30f;
    }
    float q8[8], q4[4];
#pragma unroll
    for (int r = 0; r < 8; ++r) q8[r] = fmaxf(p[r], p[r + 8]);
#pragma unroll
    for (int r = 0; r < 4; ++r) q4[r] = fmaxf(q8[r], q8[r + 4]);
    float pmax = fmaxf(fmaxf(q4[0], q4[1]), fmaxf(q4[2], q4[3]));
    pmax = fmaxf(pmax, __shfl_xor(pmax, 32));

    // deferred rescale (T13): 8 nats = 11.54 bits
    if (__any(pmax > m_run + 11.5f)) {
      float m_new = fmaxf(m_run, pmax);
      float alpha = fexp2(m_run - m_new);
      l_run *= alpha;
#pragma unroll
      for (int m2 = 0; m2 < 2; ++m2)
#pragma unroll
        for (int e = 0; e < 16; ++e) accd[m2][e] *= alpha;
      m_run = m_new;
    }

#pragma unroll
    for (int r = 0; r < 16; ++r)
      p[r] = fexp2(p[r] - m_run);        // masked: exp2(-1e30) == +0
    float s8[8], s4[4];
#pragma unroll
    for (int r = 0; r < 8; ++r) s8[r] = p[r] + p[r + 8];
#pragma unroll
    for (int r = 0; r < 4; ++r) s4[r] = s8[r] + s8[r + 4];
    float psum = (s4[0] + s4[1]) + (s4[2] + s4[3]);
    psum += __shfl_xor(psum, 32);
    l_run += psum;

    // P (D-layout) -> B-operand bf16 frags: 8 cvt_pk + 4 permlane32_swap
    bfrag pf[2];
#pragma unroll
    for (int j2 = 0; j2 < 2; ++j2) {
      u32 A0 = cvtpk(p[8 * j2 + 0], p[8 * j2 + 1]);
      u32 A1 = cvtpk(p[8 * j2 + 2], p[8 * j2 + 3]);
      u32 B0 = cvtpk(p[8 * j2 + 4], p[8 * j2 + 5]);
      u32 B1 = cvtpk(p[8 * j2 + 6], p[8 * j2 + 7]);
      permswap(A0, B0);
      permswap(A1, B1);
      union { u32 u[4]; bfrag f; } pu;
      pu.u[0] = A0; pu.u[1] = A1; pu.u[2] = B0; pu.u[3] = B1;
      pf[j2] = pu.f;
    }
    __builtin_amdgcn_s_setprio(1);
#pragma unroll
    for (int j2 = 0; j2 < 2; ++j2)
#pragma unroll
      for (int m2 = 0; m2 < 2; ++m2)
        accd[m2] = __builtin_amdgcn_mfma_f32_32x32x16_bf16(vf[j2 * 2 + m2], pf[j2], accd[m2], 0, 0, 0);
    __builtin_amdgcn_s_setprio(0);

    __syncthreads();   // drains stage DMA + LDS reads; swap buffers
    mw = mn;
  }

  // ---- merge the two s-halves through LDS (comb aliases staging buffers) --
  if (grp == 1) {
#pragma unroll
    for (int m2 = 0; m2 < 2; ++m2)
#pragma unroll
      for (int e = 0; e < 16; ++e)
        comb[wl * 2048 + (m2 * 16 + e) * 64 + lane] = accd[m2][e];
    if (hi == 0) {
      mlb[(wl * 32 + ln) * 2]     = m_run;
      mlb[(wl * 32 + ln) * 2 + 1] = l_run;
    }
  }
  __syncthreads();
  if (grp == 0) {
    float m1v = mlb[(wl * 32 + ln) * 2];
    float l1v = mlb[(wl * 32 + ln) * 2 + 1];
    float M  = fmaxf(m_run, m1v);
    float w0 = fexp2(m_run - M), w1 = fexp2(m1v - M);
    float l  = l_run * w0 + l1v * w1;
    float invl = (l > 0.f) ? 1.f / l : 0.f;
    u16* Orow = X2 + (((size_t)b << 10) + t) * C_SZ + h * DK;
#pragma unroll
    for (int m2 = 0; m2 < 2; ++m2)
#pragma unroll
      for (int g = 0; g < 4; ++g) {
        u16x4 pk4;
#pragma unroll
        for (int qq = 0; qq < 4; ++qq) {
          int e = 4 * g + qq;
          float v2 = comb[wl * 2048 + (m2 * 16 + e) * 64 + lane];
          pk4[qq] = f2bf((accd[m2][e] * w0 + v2 * w1) * invl);
        }
        *(u16x4*)(Orow + m2 * 32 + 8 * g + 4 * hi) = pk4;
      }
  }
}

extern "C" void kernel_launch(void* const* d_in, const int* in_sizes, int n_in,
                              void* d_out, int out_size, void* d_ws, size_t ws_size,
                              hipStream_t stream) {
  (void)in_sizes; (void)n_in; (void)out_size; (void)ws_size;
  const float* q    = (const float*)d_in[0];
  const float* k    = (const float*)d_in[1];
  const float* v    = (const float*)d_in[2];
  const int*   mask = (const int*)d_in[3];
  const float* Ws   = (const float*)d_in[4];
  const float* bs   = (const float*)d_in[5];
  const float* gam  = (const float*)d_in[6];
  const float* beta = (const float*)d_in[7];
  const float* mean = (const float*)d_in[8];
  const float* var  = (const float*)d_in[9];

  float* out   = (float*)d_out;
  float* cache = out + (size_t)B_SZ * C_SZ * T_SZ;     // 4,194,304 floats

  const size_t ARR = (size_t)B_SZ * T_SZ * C_SZ;       // 4,194,304 elems
  char* ws = (char*)d_ws;
  u16*   Wp = (u16*)(ws);                              // 4*512*512 bf16 = 2 MB
  float* bp = (float*)(ws + 2097152);                  // 2048 f32
  u16*   Xt = (u16*)(ws + 2162688);                    // 3 * ARR bf16
  u16*   Qt = Xt + 3 * ARR;                            // Qf fragment layout
  u16*   Kt = Qt + ARR;                                // Kf fragment layout
  u16*   Vb = Kt + ARR;                                // Vf fragment layout
  u16*   X2 = Vb + ARR;
  u32*   mb = (u32*)((char*)(X2 + ARR));               // 262144 words = 1 MB

  prologue<<<16904, 256, 0, stream>>>(q, k, v, mask, Ws, bs, gam, beta, mean, var,
                                      Xt, cache, Wp, bp, mb);
  gemm_qkv<<<dim3(8, 4, 24), 256, 0, stream>>>(Wp, bp, Xt, Qt, Kt, Vb);
  attn_fused<<<512, 512, 0, stream>>>(Qt, Kt, Vb, mb, X2);
  gemm_out<<<dim3(16, 4, 8), 256, 0, stream>>>(Wp + 786432, bp + 1536, X2, out);
}

// Round 13
// 95.301 us; speedup vs baseline: 4.1983x; 1.0414x over previous
//
#include <hip/hip_runtime.h>

typedef unsigned short u16;
typedef unsigned int   u32;
typedef short  bfrag   __attribute__((ext_vector_type(8)));   // 8 bf16 = 4 VGPR
typedef float  accfrag __attribute__((ext_vector_type(16)));  // 32x32 C/D
typedef unsigned int   u32x4 __attribute__((ext_vector_type(4)));
typedef unsigned short u16x4 __attribute__((ext_vector_type(4)));
typedef float          f32x4 __attribute__((ext_vector_type(4)));

#define B_SZ 8
#define C_SZ 512
#define T_SZ 1024
#define NH   8
#define DK   64

// 1/sqrt(d_k) * 1/ln(2): folded into Q projection; softmax runs in exp2 domain
#define QSCL 0.18033688f

__device__ __forceinline__ u16 f2bf(float f) {
  u32 u = __float_as_uint(f);
  u = u + 0x7fffu + ((u >> 16) & 1u);   // RNE
  return (u16)(u >> 16);
}

// single v_exp_f32 (exp2f libm path is ~10 instrs — measured VALU regression r4)
__device__ __forceinline__ float fexp2(float x) {
  return __builtin_amdgcn_exp2f(x);
}

__device__ __forceinline__ u32 cvtpk(float lo, float hi) {
  u32 r;
  asm("v_cvt_pk_bf16_f32 %0, %1, %2" : "=v"(r) : "v"(lo), "v"(hi));
  return r;
}

__device__ __forceinline__ void permswap(u32 &a, u32 &b) {
  asm volatile("v_permlane32_swap_b32 %0, %1" : "+v"(a), "+v"(b));
}

// async global->LDS, 16B per lane; LDS dest is wave-uniform base + lane*16
__device__ __forceinline__ void gload16(const u16* g, u16* l) {
  __builtin_amdgcn_global_load_lds(
      (const __attribute__((address_space(1))) void*)g,
      (__attribute__((address_space(3))) void*)l, 16, 0, 0);
}

// ---- merged: W' = W * inv (bf16); b' = b*inv + beta - mean*inv -----------
__global__ void prep_wb(const float* __restrict__ Ws, const float* __restrict__ bs,
                        const float* __restrict__ gam, const float* __restrict__ beta,
                        const float* __restrict__ mean, const float* __restrict__ var,
                        u16* __restrict__ Wp, float* __restrict__ bp) {
  int bx = blockIdx.x;
  if (bx < 4096) {
    int idx = bx * 256 + threadIdx.x;            // 4*512*512
    int io = idx >> 9;                           // i*512 + o
    float inv = gam[io] * rsqrtf(var[io] + 1e-5f);
    Wp[idx] = f2bf(Ws[idx] * inv);
  } else {
    int idx = (bx - 4096) * 256 + threadIdx.x;   // 2048
    float inv = gam[idx] * rsqrtf(var[idx] + 1e-5f);
    bp[idx] = bs[idx] * inv + beta[idx] - mean[idx] * inv;
  }
}

// ---- in[b][c][t] f32 -> Xt[src][b][t][c] bf16; k,v also copied to cache --
// G13 fix (r12 post-mortem): float4 loads (16B/lane), float4 cache stores,
// cvt_pk packing (2 instr vs 4 f2bf = ~24 VALU), u16x4 (8B) output stores.
__global__ void transpose_cvt(const float* __restrict__ q, const float* __restrict__ k,
                              const float* __restrict__ v, u16* __restrict__ Xt,
                              float* __restrict__ cache) {
  __shared__ float tile[32][33];
  int z = blockIdx.z;
  int src = z >> 3, b = z & 7;
  const float* in = (src == 0) ? q : ((src == 1) ? k : v);
  u16* out = Xt + (size_t)src * ((size_t)B_SZ * T_SZ * C_SZ);
  int t0 = blockIdx.x * 32, c0 = blockIdx.y * 32;
  int cy  = threadIdx.x >> 3;    // 0..31: c row
  int tx4 = threadIdx.x & 7;     // 0..7:  t offset = 4*tx4

  f32x4 v4 = *(const f32x4*)(in + (((size_t)b * C_SZ + c0 + cy) << 10) + t0 + tx4 * 4);
  if (src >= 1) {   // cache = concat(key, value) along channel dim
    int cc = c0 + cy + (src == 2 ? 512 : 0);
    *(f32x4*)(cache + ((size_t)b << 20) + ((size_t)cc << 10) + t0 + tx4 * 4) = v4;
  }
  // tile[ci][ti] = in[c0+ci][t0+ti]; 33-pad -> ~2-way bank alias (free, m136)
  tile[cy][tx4 * 4 + 0] = v4[0];
  tile[cy][tx4 * 4 + 1] = v4[1];
  tile[cy][tx4 * 4 + 2] = v4[2];
  tile[cy][tx4 * 4 + 3] = v4[3];
  __syncthreads();
  // out[t=t0+cy][c=c0+4*tx4+i] = tile[4*tx4+i][cy]
  float w0 = tile[tx4 * 4 + 0][cy];
  float w1 = tile[tx4 * 4 + 1][cy];
  float w2 = tile[tx4 * 4 + 2][cy];
  float w3 = tile[tx4 * 4 + 3][cy];
  u32 lo = cvtpk(w0, w1), hi = cvtpk(w2, w3);
  u32* orow = (u32*)(out + (((size_t)(b << 10) + t0 + cy) * C_SZ) + c0 + tx4 * 4);
  orow[0] = lo;
  orow[1] = hi;
}

// ---- mask (B,1,T,T) int32 -> bit-plane mbT[b][s/32][t] via ballot --------
// Wave handles 512 ints (8 rounds x 64 lanes); round j: lanes read consecutive
// 256B, one 64-bit ballot emits words st=half*16+2j, +1. Replaces per-word
// 8 int4 loads + ~80 shift/or with 1 load + 1 cmp + 1 ballot per 64 ints.
__global__ void mask_bits(const int* __restrict__ mask, u32* __restrict__ mbT) {
  int gw   = (blockIdx.x * 256 + threadIdx.x) >> 6;   // global wave id 0..16383
  int lane = threadIdx.x & 63;
  int bt   = gw >> 1;                                 // b*1024 + t
  int half = gw & 1;                                  // which 512-int half
  const int* base = mask + ((size_t)bt << 10) + half * 512 + lane;
  int b = bt >> 10, t = bt & 1023;
  u32* obase = mbT + (((size_t)b * 32 + half * 16) << 10) + t;
#pragma unroll
  for (int j = 0; j < 8; ++j) {
    unsigned long long bal = __ballot(base[j * 64] != 0);
    if (lane == 0)  obase[(size_t)(2 * j + 0) << 10] = (u32)bal;
    if (lane == 32) obase[(size_t)(2 * j + 1) << 10] = (u32)(bal >> 32);
  }
}

// ---- fused QKV projection GEMM (one dispatch, 768 blocks = 3/CU) ---------
// src = blockIdx.z>>3: 0->Qf (scaled by QSCL), 1->Kf, 2->Vf fragment layouts
// K-loop: reg-prefetch pipeline (load kt+1 under compute kt) + XOR-swizzled LDS
__launch_bounds__(256, 4)
__global__ void gemm_qkv(const u16* __restrict__ Wp, const float* __restrict__ bpA,
                         const u16* __restrict__ Xt,
                         u16* __restrict__ Qf, u16* __restrict__ Kf, u16* __restrict__ Vf) {
  __shared__ __align__(16) u16 lds[2 * 128 * 64];
  int tid = threadIdx.x;
  int src = blockIdx.z >> 3;
  int b   = blockIdx.z & 7;
  int t0 = blockIdx.x * 128;
  int o0 = blockIdx.y * 128;
  int wid = tid >> 6, lane = tid & 63;
  int ln = lane & 31, hi = lane >> 5;
  int wr = wid >> 1, wc = wid & 1;

  const u16* Wsrc = Wp + (size_t)src * 262144;
  const float* bp = bpA + src * 512;
  const u16* Xin  = Xt + (size_t)src * ((size_t)B_SZ * T_SZ * C_SZ);
  u16* Yout = (src == 0) ? Qf : (src == 1 ? Kf : Vf);

  const char* Ag = (const char*)Wsrc;                                    // rows: o (1024 B stride)
  const char* Bg = (const char*)(Xin + (((size_t)b << 10) + t0) * C_SZ); // rows: t-local
  char* ldsA = (char*)lds;
  char* ldsB = (char*)lds + 16384;

  accfrag acc[2][2];
#pragma unroll
  for (int m2 = 0; m2 < 2; ++m2)
#pragma unroll
    for (int n2 = 0; n2 < 2; ++n2)
#pragma unroll
      for (int e = 0; e < 16; ++e) acc[m2][n2][e] = 0.f;

  int lin = tid * 16;
  u32x4 ra[4], rb[4];
#pragma unroll
  for (int it = 0; it < 4; ++it) {   // prologue: load kt=0
    int off = lin + it * 4096;
    int r = off >> 7, cb = off & 127;
    ra[it] = *(const u32x4*)(Ag + (size_t)(o0 + r) * 1024 + cb);
    rb[it] = *(const u32x4*)(Bg + (size_t)r * 1024 + cb);
  }

  for (int kt = 0; kt < 8; ++kt) {
    __syncthreads();   // LDS free (previous compute done by all waves)
#pragma unroll
    for (int it = 0; it < 4; ++it) {
      int off = lin + it * 4096;
      int swz = off ^ (((off >> 7) & 7) << 4);   // bank swizzle (G4)
      *(u32x4*)(ldsA + swz) = ra[it];
      *(u32x4*)(ldsB + swz) = rb[it];
    }
    __syncthreads();   // LDS ready
    if (kt < 7) {      // prefetch kt+1; latency hides under the MFMA cluster
#pragma unroll
      for (int it = 0; it < 4; ++it) {
        int off = lin + it * 4096;
        int r = off >> 7, cb = off & 127;
        ra[it] = *(const u32x4*)(Ag + (size_t)(o0 + r) * 1024 + (kt + 1) * 128 + cb);
        rb[it] = *(const u32x4*)(Bg + (size_t)r * 1024 + (kt + 1) * 128 + cb);
      }
    }
#pragma unroll
    for (int kk = 0; kk < 4; ++kk) {
      int csw = (kk * 32 + hi * 16) ^ ((ln & 7) << 4);   // swizzled col
      bfrag a[2], bb[2];
#pragma unroll
      for (int m2 = 0; m2 < 2; ++m2)
        a[m2] = *(const bfrag*)(ldsA + (wr * 64 + m2 * 32 + ln) * 128 + csw);
#pragma unroll
      for (int n2 = 0; n2 < 2; ++n2)
        bb[n2] = *(const bfrag*)(ldsB + (wc * 64 + n2 * 32 + ln) * 128 + csw);
#pragma unroll
      for (int m2 = 0; m2 < 2; ++m2)
#pragma unroll
        for (int n2 = 0; n2 < 2; ++n2)
          acc[m2][n2] = __builtin_amdgcn_mfma_f32_32x32x16_bf16(a[m2], bb[n2], acc[m2][n2], 0, 0, 0);
    }
  }

  float oscl = (src == 0) ? QSCL : 1.0f;
#pragma unroll
  for (int m2 = 0; m2 < 2; ++m2) {
    int obase = o0 + wr * 64 + m2 * 32;
#pragma unroll
    for (int n2 = 0; n2 < 2; ++n2) {
      int t = t0 + wc * 64 + n2 * 32 + ln;
      if (src < 2) {
        // Q/K fragment layout: [(b*8+h)*32 + t/32][dd>>4][(t&31)+32*((dd>>3)&1)][dd&7]
        int tt5 = t & 31, st = t >> 5;
#pragma unroll
        for (int g = 0; g < 4; ++g) {
          int d0 = obase + 8 * g + 4 * hi;
          int hh = d0 >> 6, dd = d0 & 63;
          u16x4 pk4;
#pragma unroll
          for (int qq = 0; qq < 4; ++qq)
            pk4[qq] = f2bf((acc[m2][n2][4 * g + qq] + bp[d0 + qq]) * oscl);
          size_t a = ((((size_t)b * 8 + hh) * 32 + st) << 11)
                   + (size_t)((dd >> 4) * 512 + (tt5 + 32 * ((dd >> 3) & 1)) * 8 + (dd & 7));
          *(u16x4*)(Yout + a) = pk4;
        }
      } else {
        // V-fragment layout: fi=((s>>4)&1)*2+((dd>>5)&1), l=(dd&31)+((s>>3)&1)*32
        int s = t, st = s >> 5;
#pragma unroll
        for (int r = 0; r < 16; ++r) {
          int d = obase + (r & 3) + 8 * (r >> 2) + 4 * hi;
          int hh = d >> 6, dd = d & 63;
          int fi = ((s >> 4) & 1) * 2 + ((dd >> 5) & 1);
          int l  = (dd & 31) + ((s >> 3) & 1) * 32;
          Yout[((((size_t)b * 8 + hh) * 32 + st) << 11)
               + (size_t)(fi * 512 + l * 8 + (s & 7))] = f2bf(acc[m2][n2][r] + bp[d]);
        }
      }
    }
  }
}

// ---- out projection GEMM: f32 natural [b][c][t] --------------------------
// 128(o) x 64(t) tiles -> 512 blocks = 2/CU. Reg-prefetch + swizzle; LDS 24KB.
__launch_bounds__(256, 4)
__global__ void gemm_out(const u16* __restrict__ Wp, const float* __restrict__ bp,
                         const u16* __restrict__ Xin, float* __restrict__ Yout) {
  __shared__ __align__(16) char ldsc[24576];   // A 16KB | B 8KB
  int tid = threadIdx.x;
  int b  = blockIdx.z;
  int t0 = blockIdx.x * 64;
  int o0 = blockIdx.y * 128;
  int wid = tid >> 6, lane = tid & 63;
  int ln = lane & 31, hi = lane >> 5;
  int wr = wid >> 1, wc = wid & 1;

  const char* Ag = (const char*)Wp;                                      // rows: o
  const char* Bg = (const char*)(Xin + (((size_t)b << 10) + t0) * C_SZ); // rows: t-local
  char* ldsA = ldsc;
  char* ldsB = ldsc + 16384;

  accfrag acc[2];
#pragma unroll
  for (int m2 = 0; m2 < 2; ++m2)
#pragma unroll
    for (int e = 0; e < 16; ++e) acc[m2][e] = 0.f;

  int lin = tid * 16;
  u32x4 ra[4], rb[2];
#pragma unroll
  for (int it = 0; it < 4; ++it) {
    int off = lin + it * 4096;
    int r = off >> 7, cb = off & 127;
    ra[it] = *(const u32x4*)(Ag + (size_t)(o0 + r) * 1024 + cb);
  }
#pragma unroll
  for (int it = 0; it < 2; ++it) {
    int off = lin + it * 4096;
    int r = off >> 7, cb = off & 127;
    rb[it] = *(const u32x4*)(Bg + (size_t)r * 1024 + cb);
  }

  for (int kt = 0; kt < 8; ++kt) {
    __syncthreads();
#pragma unroll
    for (int it = 0; it < 4; ++it) {
      int off = lin + it * 4096;
      int swz = off ^ (((off >> 7) & 7) << 4);
      *(u32x4*)(ldsA + swz) = ra[it];
    }
#pragma unroll
    for (int it = 0; it < 2; ++it) {
      int off = lin + it * 4096;
      int swz = off ^ (((off >> 7) & 7) << 4);
      *(u32x4*)(ldsB + swz) = rb[it];
    }
    __syncthreads();
    if (kt < 7) {
#pragma unroll
      for (int it = 0; it < 4; ++it) {
        int off = lin + it * 4096;
        int r = off >> 7, cb = off & 127;
        ra[it] = *(const u32x4*)(Ag + (size_t)(o0 + r) * 1024 + (kt + 1) * 128 + cb);
      }
#pragma unroll
      for (int it = 0; it < 2; ++it) {
        int off = lin + it * 4096;
        int r = off >> 7, cb = off & 127;
        rb[it] = *(const u32x4*)(Bg + (size_t)r * 1024 + (kt + 1) * 128 + cb);
      }
    }
#pragma unroll
    for (int kk = 0; kk < 4; ++kk) {
      int csw = (kk * 32 + hi * 16) ^ ((ln & 7) << 4);
      bfrag a[2], bb;
#pragma unroll
      for (int m2 = 0; m2 < 2; ++m2)
        a[m2] = *(const bfrag*)(ldsA + (wr * 64 + m2 * 32 + ln) * 128 + csw);
      bb = *(const bfrag*)(ldsB + (wc * 32 + ln) * 128 + csw);
#pragma unroll
      for (int m2 = 0; m2 < 2; ++m2)
        acc[m2] = __builtin_amdgcn_mfma_f32_32x32x16_bf16(a[m2], bb, acc[m2], 0, 0, 0);
    }
  }

#pragma unroll
  for (int m2 = 0; m2 < 2; ++m2) {
    int obase = o0 + wr * 64 + m2 * 32;
    int t = t0 + wc * 32 + ln;
#pragma unroll
    for (int r = 0; r < 16; ++r) {
      int o = obase + (r & 3) + 8 * (r >> 2) + 4 * hi;
      Yout[(((size_t)b * C_SZ + o) << 10) + t] = acc[m2][r] + bp[o];
    }
  }
}

// ---- fused flash attention (r9 2-way s-split — best measured, LOCKED) ----
// 512 blocks x 512 thr: 2 s-groups x 4 q-tiles. Double-buffered staging:
// DMA next tile issued at top of iter, drained at bottom barrier -> latency
// hides under the whole compute phase. 4-way split falsified twice (r8/r11).
__launch_bounds__(512, 4)
__global__ void attn_fused(const u16* __restrict__ Qf, const u16* __restrict__ Kf,
                           const u16* __restrict__ Vf, const u32* __restrict__ mbT,
                           u16* __restrict__ X2) {
  __shared__ __align__(16) char smem[33 * 1024];
  u16*   sK   = (u16*)smem;             // [grp:2][buf:2][2048] = 16 KB
  u16*   sV   = (u16*)(smem + 16384);   // [grp:2][buf:2][2048] = 16 KB
  float* comb = (float*)smem;           // aliases sK/sV post-loop
  float* mlb  = (float*)(smem + 32768); // 4*32*2 f32 = 1 KB

  int n = blockIdx.x;
  int bh = n & 63, tb = n >> 6;
  int b = bh >> 3, h = bh & 7;
  int tid = threadIdx.x;
  int wid = tid >> 6, lane = tid & 63;
  int grp = wid >> 2, wl = wid & 3;
  int ln = lane & 31, hi = lane >> 5;
  int tt = tb * 4 + wl;
  int t  = tt * 32 + ln;

  // Q fragments: one coalesced 1KB load per j
  const u16* QfT = Qf + (((size_t)bh * 32 + tt) << 11);
  bfrag qf[4];
#pragma unroll
  for (int j = 0; j < 4; ++j)
    qf[j] = *(const bfrag*)(QfT + j * 512 + lane * 8);

  const u16* KfB = Kf + ((size_t)bh << 16);
  const u16* VfB = Vf + ((size_t)bh << 16);
  const u32* mcol = mbT + ((size_t)b << 15) + t;

  // m_run floor -1e4: masked scores stay -1e30 -> exp2(-1e30-m) == +0 in HW.
  float m_run = -1.0e4f, l_run = 0.f;
  accfrag accd[2];
#pragma unroll
  for (int m2 = 0; m2 < 2; ++m2)
#pragma unroll
    for (int e = 0; e < 16; ++e) accd[m2][e] = 0.f;

  int gtid = tid & 255;
  int soff = gtid * 8;                      // u16 offset: 16B per thread, per 4-wave group
  u16* sKg = sK + grp * 4096;               // this group's [buf][2048]
  u16* sVg = sV + grp * 4096;
  int st0 = grp * 16;

  // prologue: stage this group's tile 0, load mask word
  gload16(KfB + ((size_t)st0 << 11) + soff, sKg + soff);
  gload16(VfB + ((size_t)st0 << 11) + soff, sVg + soff);
  u32 mw = mcol[st0 << 10];
  __syncthreads();

#pragma unroll 2
  for (int it = 0; it < 16; ++it) {
    int cur = it & 1, nxt = cur ^ 1;
    int st = st0 + it;
    u32 mn = 0;
    if (it < 15) {   // stage next tile; latency spans the whole compute phase
      size_t tn = (size_t)(st + 1) << 11;
      gload16(KfB + tn + soff, sKg + nxt * 2048 + soff);
      gload16(VfB + tn + soff, sVg + nxt * 2048 + soff);
      mn = mcol[(st + 1) << 10];
    }

    // fragments from LDS (lane-linear -> conflict-free b128 reads)
    bfrag kf[4], vf[4];
#pragma unroll
    for (int j = 0; j < 4; ++j) {
      kf[j] = *(const bfrag*)(sKg + cur * 2048 + j * 512 + lane * 8);
      vf[j] = *(const bfrag*)(sVg + cur * 2048 + j * 512 + lane * 8);
    }

    // QK^T (S already in log2 units: Q pre-scaled)
    accfrag S;
#pragma unroll
    for (int e = 0; e < 16; ++e) S[e] = 0.f;
    __builtin_amdgcn_s_setprio(1);
#pragma unroll
    for (int j = 0; j < 4; ++j)
      S = __builtin_amdgcn_mfma_f32_32x32x16_bf16(kf[j], qf[j], S, 0, 0, 0);
    __builtin_amdgcn_s_setprio(0);

    // ---- softmax over key rows (per-lane: 16 of 32 rows; partner lane^32)
    u32 mbits = mw >> (4 * hi);          // bit positions compile-time per r
    float p[16];
#pragma unroll
    for (int r = 0; r < 16; ++r) {
      int pos = (r & 3) + 8 * (r >> 2);  // const -> v_bfe + cndmask
      p[r] = ((mbits >> pos) & 1u) ? S[r] : -1e30f;
    }
    float q8[8], q4[4];
#pragma unroll
    for (int r = 0; r < 8; ++r) q8[r] = fmaxf(p[r], p[r + 8]);
#pragma unroll
    for (int r = 0; r < 4; ++r) q4[r] = fmaxf(q8[r], q8[r + 4]);
    float pmax = fmaxf(fmaxf(q4[0], q4[1]), fmaxf(q4[2], q4[3]));
    pmax = fmaxf(pmax, __shfl_xor(pmax, 32));

    // deferred rescale (T13): 8 nats = 11.54 bits
    if (__any(pmax > m_run + 11.5f)) {
      float m_new = fmaxf(m_run, pmax);
      float alpha = fexp2(m_run - m_new);
      l_run *= alpha;
#pragma unroll
      for (int m2 = 0; m2 < 2; ++m2)
#pragma unroll
        for (int e = 0; e < 16; ++e) accd[m2][e] *= alpha;
      m_run = m_new;
    }

#pragma unroll
    for (int r = 0; r < 16; ++r)
      p[r] = fexp2(p[r] - m_run);        // masked: exp2(-1e30) == +0
    float s8[8], s4[4];
#pragma unroll
    for (int r = 0; r < 8; ++r) s8[r] = p[r] + p[r + 8];
#pragma unroll
    for (int r = 0; r < 4; ++r) s4[r] = s8[r] + s8[r + 4];
    float psum = (s4[0] + s4[1]) + (s4[2] + s4[3]);
    psum += __shfl_xor(psum, 32);
    l_run += psum;

    // P (D-layout) -> B-operand bf16 frags: 8 cvt_pk + 4 permlane32_swap
    bfrag pf[2];
#pragma unroll
    for (int j2 = 0; j2 < 2; ++j2) {
      u32 A0 = cvtpk(p[8 * j2 + 0], p[8 * j2 + 1]);
      u32 A1 = cvtpk(p[8 * j2 + 2], p[8 * j2 + 3]);
      u32 B0 = cvtpk(p[8 * j2 + 4], p[8 * j2 + 5]);
      u32 B1 = cvtpk(p[8 * j2 + 6], p[8 * j2 + 7]);
      permswap(A0, B0);
      permswap(A1, B1);
      union { u32 u[4]; bfrag f; } pu;
      pu.u[0] = A0; pu.u[1] = A1; pu.u[2] = B0; pu.u[3] = B1;
      pf[j2] = pu.f;
    }
    __builtin_amdgcn_s_setprio(1);
#pragma unroll
    for (int j2 = 0; j2 < 2; ++j2)
#pragma unroll
      for (int m2 = 0; m2 < 2; ++m2)
        accd[m2] = __builtin_amdgcn_mfma_f32_32x32x16_bf16(vf[j2 * 2 + m2], pf[j2], accd[m2], 0, 0, 0);
    __builtin_amdgcn_s_setprio(0);

    __syncthreads();   // drains stage DMA + LDS reads; swap buffers
    mw = mn;
  }

  // ---- merge the two s-halves through LDS (comb aliases staging buffers) --
  if (grp == 1) {
#pragma unroll
    for (int m2 = 0; m2 < 2; ++m2)
#pragma unroll
      for (int e = 0; e < 16; ++e)
        comb[wl * 2048 + (m2 * 16 + e) * 64 + lane] = accd[m2][e];
    if (hi == 0) {
      mlb[(wl * 32 + ln) * 2]     = m_run;
      mlb[(wl * 32 + ln) * 2 + 1] = l_run;
    }
  }
  __syncthreads();
  if (grp == 0) {
    float m1v = mlb[(wl * 32 + ln) * 2];
    float l1v = mlb[(wl * 32 + ln) * 2 + 1];
    float M  = fmaxf(m_run, m1v);
    float w0 = fexp2(m_run - M), w1 = fexp2(m1v - M);
    float l  = l_run * w0 + l1v * w1;
    float invl = (l > 0.f) ? 1.f / l : 0.f;
    u16* Orow = X2 + (((size_t)b << 10) + t) * C_SZ + h * DK;
#pragma unroll
    for (int m2 = 0; m2 < 2; ++m2)
#pragma unroll
      for (int g = 0; g < 4; ++g) {
        u16x4 pk4;
#pragma unroll
        for (int qq = 0; qq < 4; ++qq) {
          int e = 4 * g + qq;
          float v2 = comb[wl * 2048 + (m2 * 16 + e) * 64 + lane];
          pk4[qq] = f2bf((accd[m2][e] * w0 + v2 * w1) * invl);
        }
        *(u16x4*)(Orow + m2 * 32 + 8 * g + 4 * hi) = pk4;
      }
  }
}

extern "C" void kernel_launch(void* const* d_in, const int* in_sizes, int n_in,
                              void* d_out, int out_size, void* d_ws, size_t ws_size,
                              hipStream_t stream) {
  (void)in_sizes; (void)n_in; (void)out_size; (void)ws_size;
  const float* q    = (const float*)d_in[0];
  const float* k    = (const float*)d_in[1];
  const float* v    = (const float*)d_in[2];
  const int*   mask = (const int*)d_in[3];
  const float* Ws   = (const float*)d_in[4];
  const float* bs   = (const float*)d_in[5];
  const float* gam  = (const float*)d_in[6];
  const float* beta = (const float*)d_in[7];
  const float* mean = (const float*)d_in[8];
  const float* var  = (const float*)d_in[9];

  float* out   = (float*)d_out;
  float* cache = out + (size_t)B_SZ * C_SZ * T_SZ;     // 4,194,304 floats

  const size_t ARR = (size_t)B_SZ * T_SZ * C_SZ;       // 4,194,304 elems
  char* ws = (char*)d_ws;
  u16*   Wp = (u16*)(ws);                              // 4*512*512 bf16 = 2 MB
  float* bp = (float*)(ws + 2097152);                  // 2048 f32
  u16*   Xt = (u16*)(ws + 2162688);                    // 3 * ARR bf16
  u16*   Qt = Xt + 3 * ARR;                            // Qf fragment layout
  u16*   Kt = Qt + ARR;                                // Kf fragment layout
  u16*   Vb = Kt + ARR;                                // Vf fragment layout
  u16*   X2 = Vb + ARR;
  u32*   mb = (u32*)((char*)(X2 + ARR));               // 262144 words = 1 MB

  prep_wb<<<4104, 256, 0, stream>>>(Ws, bs, gam, beta, mean, var, Wp, bp);
  transpose_cvt<<<dim3(32, 16, 24), 256, 0, stream>>>(q, k, v, Xt, cache);
  mask_bits<<<4096, 256, 0, stream>>>(mask, mb);

  gemm_qkv<<<dim3(8, 4, 24), 256, 0, stream>>>(Wp, bp, Xt, Qt, Kt, Vb);
  attn_fused<<<512, 512, 0, stream>>>(Qt, Kt, Vb, mb, X2);
  gemm_out<<<dim3(16, 4, 8), 256, 0, stream>>>(Wp + 786432, bp + 1536, X2, out);
}

// Round 14
// 93.485 us; speedup vs baseline: 4.2799x; 1.0194x over previous
//
#include <hip/hip_runtime.h>

typedef unsigned short u16;
typedef unsigned int   u32;
typedef short  bfrag   __attribute__((ext_vector_type(8)));   // 8 bf16 = 4 VGPR
typedef float  accfrag __attribute__((ext_vector_type(16)));  // 32x32 C/D
typedef unsigned int   u32x4 __attribute__((ext_vector_type(4)));
typedef unsigned short u16x4 __attribute__((ext_vector_type(4)));
typedef float          f32x4 __attribute__((ext_vector_type(4)));

#define B_SZ 8
#define C_SZ 512
#define T_SZ 1024
#define NH   8
#define DK   64

// 1/sqrt(d_k) * 1/ln(2): folded into Q projection; softmax runs in exp2 domain
#define QSCL 0.18033688f

__device__ __forceinline__ u16 f2bf(float f) {
  u32 u = __float_as_uint(f);
  u = u + 0x7fffu + ((u >> 16) & 1u);   // RNE
  return (u16)(u >> 16);
}

// single v_exp_f32 (exp2f libm path is ~10 instrs — measured VALU regression r4)
__device__ __forceinline__ float fexp2(float x) {
  return __builtin_amdgcn_exp2f(x);
}

__device__ __forceinline__ u32 cvtpk(float lo, float hi) {
  u32 r;
  asm("v_cvt_pk_bf16_f32 %0, %1, %2" : "=v"(r) : "v"(lo), "v"(hi));
  return r;
}

__device__ __forceinline__ void permswap(u32 &a, u32 &b) {
  asm volatile("v_permlane32_swap_b32 %0, %1" : "+v"(a), "+v"(b));
}

// async global->LDS, 16B per lane; LDS dest is wave-uniform base + lane*16
__device__ __forceinline__ void gload16(const u16* g, u16* l) {
  __builtin_amdgcn_global_load_lds(
      (const __attribute__((address_space(1))) void*)g,
      (__attribute__((address_space(3))) void*)l, 16, 0, 0);
}

// ---- merged small prep: W'/b' (bx<4104) | mask bit-plane (ballot) --------
__global__ void prep_mask(const float* __restrict__ Ws, const float* __restrict__ bs,
                          const float* __restrict__ gam, const float* __restrict__ beta,
                          const float* __restrict__ mean, const float* __restrict__ var,
                          const int* __restrict__ mask,
                          u16* __restrict__ Wp, float* __restrict__ bp,
                          u32* __restrict__ mbT) {
  int bx = blockIdx.x;
  if (bx < 4096) {
    int idx = bx * 256 + threadIdx.x;            // 4*512*512
    int io = idx >> 9;                           // i*512 + o
    float inv = gam[io] * rsqrtf(var[io] + 1e-5f);
    Wp[idx] = f2bf(Ws[idx] * inv);
  } else if (bx < 4104) {
    int idx = (bx - 4096) * 256 + threadIdx.x;   // 2048
    float inv = gam[idx] * rsqrtf(var[idx] + 1e-5f);
    bp[idx] = bs[idx] * inv + beta[idx] - mean[idx] * inv;
  } else {
    // mask (B,1,T,T) int32 -> bit-plane mbT[b][s/32][t] via 64-lane ballot
    int gw   = ((bx - 4104) * 256 + threadIdx.x) >> 6;  // wave id 0..16383
    int lane = threadIdx.x & 63;
    int bt   = gw >> 1;                                 // b*1024 + t
    int half = gw & 1;
    const int* base = mask + ((size_t)bt << 10) + half * 512 + lane;
    int b = bt >> 10, t = bt & 1023;
    u32* obase = mbT + (((size_t)b * 32 + half * 16) << 10) + t;
#pragma unroll
    for (int j = 0; j < 8; ++j) {
      unsigned long long bal = __ballot(base[j * 64] != 0);
      if (lane == 0)  obase[(size_t)(2 * j + 0) << 10] = (u32)bal;
      if (lane == 32) obase[(size_t)(2 * j + 1) << 10] = (u32)(bal >> 32);
    }
  }
}

// ---- in[b][c][t] f32 -> Xt[src][b][t][c] bf16; k,v also copied to cache --
// G13: float4 loads (16B/lane), float4 cache stores, cvt_pk packing, 8B stores.
__global__ void transpose_cvt(const float* __restrict__ q, const float* __restrict__ k,
                              const float* __restrict__ v, u16* __restrict__ Xt,
                              float* __restrict__ cache) {
  __shared__ float tile[32][33];
  int z = blockIdx.z;
  int src = z >> 3, b = z & 7;
  const float* in = (src == 0) ? q : ((src == 1) ? k : v);
  u16* out = Xt + (size_t)src * ((size_t)B_SZ * T_SZ * C_SZ);
  int t0 = blockIdx.x * 32, c0 = blockIdx.y * 32;
  int cy  = threadIdx.x >> 3;    // 0..31: c row
  int tx4 = threadIdx.x & 7;     // 0..7:  t offset = 4*tx4

  f32x4 v4 = *(const f32x4*)(in + (((size_t)b * C_SZ + c0 + cy) << 10) + t0 + tx4 * 4);
  if (src >= 1) {   // cache = concat(key, value) along channel dim
    int cc = c0 + cy + (src == 2 ? 512 : 0);
    *(f32x4*)(cache + ((size_t)b << 20) + ((size_t)cc << 10) + t0 + tx4 * 4) = v4;
  }
  tile[cy][tx4 * 4 + 0] = v4[0];
  tile[cy][tx4 * 4 + 1] = v4[1];
  tile[cy][tx4 * 4 + 2] = v4[2];
  tile[cy][tx4 * 4 + 3] = v4[3];
  __syncthreads();
  float w0 = tile[tx4 * 4 + 0][cy];
  float w1 = tile[tx4 * 4 + 1][cy];
  float w2 = tile[tx4 * 4 + 2][cy];
  float w3 = tile[tx4 * 4 + 3][cy];
  u32 lo = cvtpk(w0, w1), hi = cvtpk(w2, w3);
  u32* orow = (u32*)(out + (((size_t)(b << 10) + t0 + cy) * C_SZ) + c0 + tx4 * 4);
  orow[0] = lo;
  orow[1] = hi;
}

// ---- fused QKV projection GEMM (one dispatch, 768 blocks = 3/CU) ---------
// src = blockIdx.z>>3: 0->Qf (scaled by QSCL), 1->Kf, 2->Vf fragment layouts
// K-loop: reg-prefetch pipeline (load kt+1 under compute kt) + XOR-swizzled LDS
__launch_bounds__(256, 4)
__global__ void gemm_qkv(const u16* __restrict__ Wp, const float* __restrict__ bpA,
                         const u16* __restrict__ Xt,
                         u16* __restrict__ Qf, u16* __restrict__ Kf, u16* __restrict__ Vf) {
  __shared__ __align__(16) u16 lds[2 * 128 * 64];
  int tid = threadIdx.x;
  int src = blockIdx.z >> 3;
  int b   = blockIdx.z & 7;
  int t0 = blockIdx.x * 128;
  int o0 = blockIdx.y * 128;
  int wid = tid >> 6, lane = tid & 63;
  int ln = lane & 31, hi = lane >> 5;
  int wr = wid >> 1, wc = wid & 1;

  const u16* Wsrc = Wp + (size_t)src * 262144;
  const float* bp = bpA + src * 512;
  const u16* Xin  = Xt + (size_t)src * ((size_t)B_SZ * T_SZ * C_SZ);
  u16* Yout = (src == 0) ? Qf : (src == 1 ? Kf : Vf);

  const char* Ag = (const char*)Wsrc;                                    // rows: o (1024 B stride)
  const char* Bg = (const char*)(Xin + (((size_t)b << 10) + t0) * C_SZ); // rows: t-local
  char* ldsA = (char*)lds;
  char* ldsB = (char*)lds + 16384;

  accfrag acc[2][2];
#pragma unroll
  for (int m2 = 0; m2 < 2; ++m2)
#pragma unroll
    for (int n2 = 0; n2 < 2; ++n2)
#pragma unroll
      for (int e = 0; e < 16; ++e) acc[m2][n2][e] = 0.f;

  int lin = tid * 16;
  u32x4 ra[4], rb[4];
#pragma unroll
  for (int it = 0; it < 4; ++it) {   // prologue: load kt=0
    int off = lin + it * 4096;
    int r = off >> 7, cb = off & 127;
    ra[it] = *(const u32x4*)(Ag + (size_t)(o0 + r) * 1024 + cb);
    rb[it] = *(const u32x4*)(Bg + (size_t)r * 1024 + cb);
  }

  for (int kt = 0; kt < 8; ++kt) {
    __syncthreads();   // LDS free (previous compute done by all waves)
#pragma unroll
    for (int it = 0; it < 4; ++it) {
      int off = lin + it * 4096;
      int swz = off ^ (((off >> 7) & 7) << 4);   // bank swizzle (G4)
      *(u32x4*)(ldsA + swz) = ra[it];
      *(u32x4*)(ldsB + swz) = rb[it];
    }
    __syncthreads();   // LDS ready
    if (kt < 7) {      // prefetch kt+1; latency hides under the MFMA cluster
#pragma unroll
      for (int it = 0; it < 4; ++it) {
        int off = lin + it * 4096;
        int r = off >> 7, cb = off & 127;
        ra[it] = *(const u32x4*)(Ag + (size_t)(o0 + r) * 1024 + (kt + 1) * 128 + cb);
        rb[it] = *(const u32x4*)(Bg + (size_t)r * 1024 + (kt + 1) * 128 + cb);
      }
    }
#pragma unroll
    for (int kk = 0; kk < 4; ++kk) {
      int csw = (kk * 32 + hi * 16) ^ ((ln & 7) << 4);   // swizzled col
      bfrag a[2], bb[2];
#pragma unroll
      for (int m2 = 0; m2 < 2; ++m2)
        a[m2] = *(const bfrag*)(ldsA + (wr * 64 + m2 * 32 + ln) * 128 + csw);
#pragma unroll
      for (int n2 = 0; n2 < 2; ++n2)
        bb[n2] = *(const bfrag*)(ldsB + (wc * 64 + n2 * 32 + ln) * 128 + csw);
#pragma unroll
      for (int m2 = 0; m2 < 2; ++m2)
#pragma unroll
        for (int n2 = 0; n2 < 2; ++n2)
          acc[m2][n2] = __builtin_amdgcn_mfma_f32_32x32x16_bf16(a[m2], bb[n2], acc[m2][n2], 0, 0, 0);
    }
  }

  float oscl = (src == 0) ? QSCL : 1.0f;
#pragma unroll
  for (int m2 = 0; m2 < 2; ++m2) {
    int obase = o0 + wr * 64 + m2 * 32;
#pragma unroll
    for (int n2 = 0; n2 < 2; ++n2) {
      int t = t0 + wc * 64 + n2 * 32 + ln;
      if (src < 2) {
        // Q/K fragment layout: [(b*8+h)*32 + t/32][dd>>4][(t&31)+32*((dd>>3)&1)][dd&7]
        int tt5 = t & 31, st = t >> 5;
#pragma unroll
        for (int g = 0; g < 4; ++g) {
          int d0 = obase + 8 * g + 4 * hi;
          int hh = d0 >> 6, dd = d0 & 63;
          u16x4 pk4;
#pragma unroll
          for (int qq = 0; qq < 4; ++qq)
            pk4[qq] = f2bf((acc[m2][n2][4 * g + qq] + bp[d0 + qq]) * oscl);
          size_t a = ((((size_t)b * 8 + hh) * 32 + st) << 11)
                   + (size_t)((dd >> 4) * 512 + (tt5 + 32 * ((dd >> 3) & 1)) * 8 + (dd & 7));
          *(u16x4*)(Yout + a) = pk4;
        }
      } else {
        // V-fragment layout: fi=((s>>4)&1)*2+((dd>>5)&1), l=(dd&31)+((s>>3)&1)*32
        int s = t, st = s >> 5;
#pragma unroll
        for (int r = 0; r < 16; ++r) {
          int d = obase + (r & 3) + 8 * (r >> 2) + 4 * hi;
          int hh = d >> 6, dd = d & 63;
          int fi = ((s >> 4) & 1) * 2 + ((dd >> 5) & 1);
          int l  = (dd & 31) + ((s >> 3) & 1) * 32;
          Yout[((((size_t)b * 8 + hh) * 32 + st) << 11)
               + (size_t)(fi * 512 + l * 8 + (s & 7))] = f2bf(acc[m2][n2][r] + bp[d]);
        }
      }
    }
  }
}

// ---- out projection GEMM: f32 natural [b][c][t] --------------------------
// 128(o) x 64(t) tiles -> 512 blocks = 2/CU. Reg-prefetch + swizzle; LDS 24KB.
__launch_bounds__(256, 4)
__global__ void gemm_out(const u16* __restrict__ Wp, const float* __restrict__ bp,
                         const u16* __restrict__ Xin, float* __restrict__ Yout) {
  __shared__ __align__(16) char ldsc[24576];   // A 16KB | B 8KB
  int tid = threadIdx.x;
  int b  = blockIdx.z;
  int t0 = blockIdx.x * 64;
  int o0 = blockIdx.y * 128;
  int wid = tid >> 6, lane = tid & 63;
  int ln = lane & 31, hi = lane >> 5;
  int wr = wid >> 1, wc = wid & 1;

  const char* Ag = (const char*)Wp;                                      // rows: o
  const char* Bg = (const char*)(Xin + (((size_t)b << 10) + t0) * C_SZ); // rows: t-local
  char* ldsA = ldsc;
  char* ldsB = ldsc + 16384;

  accfrag acc[2];
#pragma unroll
  for (int m2 = 0; m2 < 2; ++m2)
#pragma unroll
    for (int e = 0; e < 16; ++e) acc[m2][e] = 0.f;

  int lin = tid * 16;
  u32x4 ra[4], rb[2];
#pragma unroll
  for (int it = 0; it < 4; ++it) {
    int off = lin + it * 4096;
    int r = off >> 7, cb = off & 127;
    ra[it] = *(const u32x4*)(Ag + (size_t)(o0 + r) * 1024 + cb);
  }
#pragma unroll
  for (int it = 0; it < 2; ++it) {
    int off = lin + it * 4096;
    int r = off >> 7, cb = off & 127;
    rb[it] = *(const u32x4*)(Bg + (size_t)r * 1024 + cb);
  }

  for (int kt = 0; kt < 8; ++kt) {
    __syncthreads();
#pragma unroll
    for (int it = 0; it < 4; ++it) {
      int off = lin + it * 4096;
      int swz = off ^ (((off >> 7) & 7) << 4);
      *(u32x4*)(ldsA + swz) = ra[it];
    }
#pragma unroll
    for (int it = 0; it < 2; ++it) {
      int off = lin + it * 4096;
      int swz = off ^ (((off >> 7) & 7) << 4);
      *(u32x4*)(ldsB + swz) = rb[it];
    }
    __syncthreads();
    if (kt < 7) {
#pragma unroll
      for (int it = 0; it < 4; ++it) {
        int off = lin + it * 4096;
        int r = off >> 7, cb = off & 127;
        ra[it] = *(const u32x4*)(Ag + (size_t)(o0 + r) * 1024 + (kt + 1) * 128 + cb);
      }
#pragma unroll
      for (int it = 0; it < 2; ++it) {
        int off = lin + it * 4096;
        int r = off >> 7, cb = off & 127;
        rb[it] = *(const u32x4*)(Bg + (size_t)r * 1024 + (kt + 1) * 128 + cb);
      }
    }
#pragma unroll
    for (int kk = 0; kk < 4; ++kk) {
      int csw = (kk * 32 + hi * 16) ^ ((ln & 7) << 4);
      bfrag a[2], bb;
#pragma unroll
      for (int m2 = 0; m2 < 2; ++m2)
        a[m2] = *(const bfrag*)(ldsA + (wr * 64 + m2 * 32 + ln) * 128 + csw);
      bb = *(const bfrag*)(ldsB + (wc * 32 + ln) * 128 + csw);
#pragma unroll
      for (int m2 = 0; m2 < 2; ++m2)
        acc[m2] = __builtin_amdgcn_mfma_f32_32x32x16_bf16(a[m2], bb, acc[m2], 0, 0, 0);
    }
  }

#pragma unroll
  for (int m2 = 0; m2 < 2; ++m2) {
    int obase = o0 + wr * 64 + m2 * 32;
    int t = t0 + wc * 32 + ln;
#pragma unroll
    for (int r = 0; r < 16; ++r) {
      int o = obase + (r & 3) + 8 * (r >> 2) + 4 * hi;
      Yout[(((size_t)b * C_SZ + o) << 10) + t] = acc[m2][r] + bp[o];
    }
  }
}

// ---- fused flash attention, 2-way s-split, KVBLK=64 ----------------------
// 512 blocks x 512 thr: 2 s-groups x 4 q-tiles. Grid caps occupancy at
// 2 blocks/CU -> LDS up to 80KB is free: double KVBLK to 64 (64KB dbuf),
// halving iteration count (16->8) and per-iter fixed costs (barrier+drain,
// loop bookkeeping). Per-subtile softmax body unchanged (regs reused).
__launch_bounds__(512, 2)
__global__ void attn_fused(const u16* __restrict__ Qf, const u16* __restrict__ Kf,
                           const u16* __restrict__ Vf, const u32* __restrict__ mbT,
                           u16* __restrict__ X2) {
  __shared__ __align__(16) char smem[66560];   // K 32KB | V 32KB | mlb 1KB
  u16*   sKa  = (u16*)smem;                    // [grp:2][buf:2][4096]
  u16*   sVa  = (u16*)(smem + 32768);          // [grp:2][buf:2][4096]
  float* comb = (float*)smem;                  // aliases staging post-loop
  float* mlb  = (float*)(smem + 65536);        // 4*32*2 f32 = 1 KB

  int n = blockIdx.x;
  int bh = n & 63, tb = n >> 6;
  int b = bh >> 3, h = bh & 7;
  int tid = threadIdx.x;
  int wid = tid >> 6, lane = tid & 63;
  int grp = wid >> 2, wl = wid & 3;
  int ln = lane & 31, hi = lane >> 5;
  int tt = tb * 4 + wl;
  int t  = tt * 32 + ln;

  // Q fragments: one coalesced 1KB load per j
  const u16* QfT = Qf + (((size_t)bh * 32 + tt) << 11);
  bfrag qf[4];
#pragma unroll
  for (int j = 0; j < 4; ++j)
    qf[j] = *(const bfrag*)(QfT + j * 512 + lane * 8);

  const u16* KfB = Kf + ((size_t)bh << 16);
  const u16* VfB = Vf + ((size_t)bh << 16);
  const u32* mcol = mbT + ((size_t)b << 15) + t;

  // m_run floor -1e4: masked scores stay -1e30 -> exp2(-1e30-m) == +0 in HW.
  float m_run = -1.0e4f, l_run = 0.f;
  accfrag accd[2];
#pragma unroll
  for (int m2 = 0; m2 < 2; ++m2)
#pragma unroll
    for (int e = 0; e < 16; ++e) accd[m2][e] = 0.f;

  int gtid = tid & 255;
  int soff = gtid * 8;                      // 16B per thread per gload16 (4KB/group-call)
  u16* sKg = sKa + grp * 8192;              // this group's [buf:2][4096]
  u16* sVg = sVa + grp * 8192;
  int sp0 = grp * 8;                        // subtile-pair index base (pair = 64 keys)

  // prologue: stage pair 0 (K 8KB + V 8KB), load 2 mask words
  {
    size_t pb = (size_t)(sp0 * 2) << 11;    // u16 offset of first subtile
    gload16(KfB + pb + soff,        sKg + soff);
    gload16(KfB + pb + 2048 + soff, sKg + 2048 + soff);
    gload16(VfB + pb + soff,        sVg + soff);
    gload16(VfB + pb + 2048 + soff, sVg + 2048 + soff);
  }
  u32 mw0 = mcol[(size_t)(sp0 * 2) << 10];
  u32 mw1 = mcol[(size_t)(sp0 * 2 + 1) << 10];
  __syncthreads();

#pragma unroll 2
  for (int it = 0; it < 8; ++it) {
    int cur = it & 1, nxt = cur ^ 1;
    u32 mn0 = 0, mn1 = 0;
    if (it < 7) {   // stage next 64-key pair; latency spans whole compute phase
      size_t pb = (size_t)((sp0 + it + 1) * 2) << 11;
      gload16(KfB + pb + soff,        sKg + nxt * 4096 + soff);
      gload16(KfB + pb + 2048 + soff, sKg + nxt * 4096 + 2048 + soff);
      gload16(VfB + pb + soff,        sVg + nxt * 4096 + soff);
      gload16(VfB + pb + 2048 + soff, sVg + nxt * 4096 + 2048 + soff);
      mn0 = mcol[(size_t)((sp0 + it + 1) * 2) << 10];
      mn1 = mcol[(size_t)((sp0 + it + 1) * 2 + 1) << 10];
    }

#pragma unroll
    for (int sub = 0; sub < 2; ++sub) {
      u32 mw = (sub == 0) ? mw0 : mw1;
      // fragments from LDS (lane-linear -> conflict-free b128 reads)
      bfrag kf[4], vf[4];
#pragma unroll
      for (int j = 0; j < 4; ++j) {
        kf[j] = *(const bfrag*)(sKg + cur * 4096 + sub * 2048 + j * 512 + lane * 8);
        vf[j] = *(const bfrag*)(sVg + cur * 4096 + sub * 2048 + j * 512 + lane * 8);
      }

      // QK^T (S already in log2 units: Q pre-scaled)
      accfrag S;
#pragma unroll
      for (int e = 0; e < 16; ++e) S[e] = 0.f;
      __builtin_amdgcn_s_setprio(1);
#pragma unroll
      for (int j = 0; j < 4; ++j)
        S = __builtin_amdgcn_mfma_f32_32x32x16_bf16(kf[j], qf[j], S, 0, 0, 0);
      __builtin_amdgcn_s_setprio(0);

      // softmax over key rows (per-lane: 16 of 32 rows; partner lane^32)
      u32 mbits = mw >> (4 * hi);
      float p[16];
#pragma unroll
      for (int r = 0; r < 16; ++r) {
        int pos = (r & 3) + 8 * (r >> 2);
        p[r] = ((mbits >> pos) & 1u) ? S[r] : -1e30f;
      }
      float q8[8], q4[4];
#pragma unroll
      for (int r = 0; r < 8; ++r) q8[r] = fmaxf(p[r], p[r + 8]);
#pragma unroll
      for (int r = 0; r < 4; ++r) q4[r] = fmaxf(q8[r], q8[r + 4]);
      float pmax = fmaxf(fmaxf(q4[0], q4[1]), fmaxf(q4[2], q4[3]));
      pmax = fmaxf(pmax, __shfl_xor(pmax, 32));

      // deferred rescale (T13): 8 nats = 11.54 bits
      if (__any(pmax > m_run + 11.5f)) {
        float m_new = fmaxf(m_run, pmax);
        float alpha = fexp2(m_run - m_new);
        l_run *= alpha;
#pragma unroll
        for (int m2 = 0; m2 < 2; ++m2)
#pragma unroll
          for (int e = 0; e < 16; ++e) accd[m2][e] *= alpha;
        m_run = m_new;
      }

#pragma unroll
      for (int r = 0; r < 16; ++r)
        p[r] = fexp2(p[r] - m_run);          // masked: exp2(-1e30) == +0
      float s8[8], s4[4];
#pragma unroll
      for (int r = 0; r < 8; ++r) s8[r] = p[r] + p[r + 8];
#pragma unroll
      for (int r = 0; r < 4; ++r) s4[r] = s8[r] + s8[r + 4];
      float psum = (s4[0] + s4[1]) + (s4[2] + s4[3]);
      psum += __shfl_xor(psum, 32);
      l_run += psum;

      // P (D-layout) -> B-operand bf16 frags: 8 cvt_pk + 4 permlane32_swap
      bfrag pf[2];
#pragma unroll
      for (int j2 = 0; j2 < 2; ++j2) {
        u32 A0 = cvtpk(p[8 * j2 + 0], p[8 * j2 + 1]);
        u32 A1 = cvtpk(p[8 * j2 + 2], p[8 * j2 + 3]);
        u32 B0 = cvtpk(p[8 * j2 + 4], p[8 * j2 + 5]);
        u32 B1 = cvtpk(p[8 * j2 + 6], p[8 * j2 + 7]);
        permswap(A0, B0);
        permswap(A1, B1);
        union { u32 u[4]; bfrag f; } pu;
        pu.u[0] = A0; pu.u[1] = A1; pu.u[2] = B0; pu.u[3] = B1;
        pf[j2] = pu.f;
      }
      __builtin_amdgcn_s_setprio(1);
#pragma unroll
      for (int j2 = 0; j2 < 2; ++j2)
#pragma unroll
        for (int m2 = 0; m2 < 2; ++m2)
          accd[m2] = __builtin_amdgcn_mfma_f32_32x32x16_bf16(vf[j2 * 2 + m2], pf[j2], accd[m2], 0, 0, 0);
      __builtin_amdgcn_s_setprio(0);
    }

    __syncthreads();   // drains stage DMA + LDS reads; swap buffers
    mw0 = mn0;
    mw1 = mn1;
  }

  // ---- merge the two s-halves through LDS (comb aliases staging buffers) --
  if (grp == 1) {
#pragma unroll
    for (int m2 = 0; m2 < 2; ++m2)
#pragma unroll
      for (int e = 0; e < 16; ++e)
        comb[wl * 2048 + (m2 * 16 + e) * 64 + lane] = accd[m2][e];
    if (hi == 0) {
      mlb[(wl * 32 + ln) * 2]     = m_run;
      mlb[(wl * 32 + ln) * 2 + 1] = l_run;
    }
  }
  __syncthreads();
  if (grp == 0) {
    float m1v = mlb[(wl * 32 + ln) * 2];
    float l1v = mlb[(wl * 32 + ln) * 2 + 1];
    float M  = fmaxf(m_run, m1v);
    float w0 = fexp2(m_run - M), w1 = fexp2(m1v - M);
    float l  = l_run * w0 + l1v * w1;
    float invl = (l > 0.f) ? 1.f / l : 0.f;
    u16* Orow = X2 + (((size_t)b << 10) + t) * C_SZ + h * DK;
#pragma unroll
    for (int m2 = 0; m2 < 2; ++m2)
#pragma unroll
      for (int g = 0; g < 4; ++g) {
        u16x4 pk4;
#pragma unroll
        for (int qq = 0; qq < 4; ++qq) {
          int e = 4 * g + qq;
          float v2 = comb[wl * 2048 + (m2 * 16 + e) * 64 + lane];
          pk4[qq] = f2bf((accd[m2][e] * w0 + v2 * w1) * invl);
        }
        *(u16x4*)(Orow + m2 * 32 + 8 * g + 4 * hi) = pk4;
      }
  }
}

extern "C" void kernel_launch(void* const* d_in, const int* in_sizes, int n_in,
                              void* d_out, int out_size, void* d_ws, size_t ws_size,
                              hipStream_t stream) {
  (void)in_sizes; (void)n_in; (void)out_size; (void)ws_size;
  const float* q    = (const float*)d_in[0];
  const float* k    = (const float*)d_in[1];
  const float* v    = (const float*)d_in[2];
  const int*   mask = (const int*)d_in[3];
  const float* Ws   = (const float*)d_in[4];
  const float* bs   = (const float*)d_in[5];
  const float* gam  = (const float*)d_in[6];
  const float* beta = (const float*)d_in[7];
  const float* mean = (const float*)d_in[8];
  const float* var  = (const float*)d_in[9];

  float* out   = (float*)d_out;
  float* cache = out + (size_t)B_SZ * C_SZ * T_SZ;     // 4,194,304 floats

  const size_t ARR = (size_t)B_SZ * T_SZ * C_SZ;       // 4,194,304 elems
  char* ws = (char*)d_ws;
  u16*   Wp = (u16*)(ws);                              // 4*512*512 bf16 = 2 MB
  float* bp = (float*)(ws + 2097152);                  // 2048 f32
  u16*   Xt = (u16*)(ws + 2162688);                    // 3 * ARR bf16
  u16*   Qt = Xt + 3 * ARR;                            // Qf fragment layout
  u16*   Kt = Qt + ARR;                                // Kf fragment layout
  u16*   Vb = Kt + ARR;                                // Vf fragment layout
  u16*   X2 = Vb + ARR;
  u32*   mb = (u32*)((char*)(X2 + ARR));               // 262144 words = 1 MB

  prep_mask<<<8200, 256, 0, stream>>>(Ws, bs, gam, beta, mean, var, mask, Wp, bp, mb);
  transpose_cvt<<<dim3(32, 16, 24), 256, 0, stream>>>(q, k, v, Xt, cache);

  gemm_qkv<<<dim3(8, 4, 24), 256, 0, stream>>>(Wp, bp, Xt, Qt, Kt, Vb);
  attn_fused<<<512, 512, 0, stream>>>(Qt, Kt, Vb, mb, X2);
  gemm_out<<<dim3(16, 4, 8), 256, 0, stream>>>(Wp + 786432, bp + 1536, X2, out);
}